// Round 15
// baseline (4722.834 us; speedup 1.0000x reference)
//
#include <hip/hip_runtime.h>
#include <math.h>

// ---------------------------------------------------------------------------
// SDTP forward, round 15.
// vs r14: k_bg256 rebuilt as BK=32 / 4-buffer / counted-vmcnt pipeline
// (T3+T4 done right): stage 3 tiles ahead, per tile = {barrier; 12 ds_read +
// STAGE(T+3); 32 MFMA; vmcnt(8|4|0)} -- loads get ~2 tiles of flight, never
// drained to 0 mid-loop. Same K order per accumulator -> bit-identical.
// ---------------------------------------------------------------------------

#define DD 2048
#define HH 16
#define DHH 128
#define FFF 8192
#define BBATCH 2
#define SSEQ 2048
#define VV 32000
#define LLAYERS 4

typedef float4 f4;
typedef __attribute__((ext_vector_type(8))) short short8;
typedef __attribute__((ext_vector_type(4))) float f32x4;
typedef unsigned short u16;

__device__ inline u16 bf16rne(float x) {
    unsigned u = __float_as_uint(x);
    unsigned r = (u + 0x7FFFu + ((u >> 16) & 1u)) >> 16;
    return (u16)r;
}
__device__ inline float bf16tof(u16 h) {
    return __uint_as_float(((unsigned)h) << 16);
}

__device__ __forceinline__ void gload16(const u16* g, u16* l) {
    __builtin_amdgcn_global_load_lds(
        (const __attribute__((address_space(1))) unsigned int*)g,
        (__attribute__((address_space(3))) unsigned int*)l, 16, 0, 0);
}

#define BARRIER() do { asm volatile("" ::: "memory"); \
    __builtin_amdgcn_s_barrier(); asm volatile("" ::: "memory"); } while (0)

// bijective XCD-aware block swizzle (m204), COLUMN-major orig
__device__ __forceinline__ void xcd_swz(int& bx, int& by) {
    int gy = gridDim.y;
    int nwg = gridDim.x * gy;
    int orig = bx * gy + by;
    int q = nwg >> 3, r = nwg & 7;
    int xcd = orig & 7, loc = orig >> 3;
    int swz = (xcd < r ? xcd * (q + 1) : r * (q + 1) + (xcd - r) * q) + loc;
    bx = swz / gy;
    by = swz % gy;
}

// ---------------- embedding / copies ----------------
__global__ void k_embed(const int* __restrict__ ids, const float* __restrict__ emb,
                        float* __restrict__ out) {
    int row = blockIdx.x;
    int id  = ids[row];
    const f4* src = (const f4*)(emb + (size_t)id * DD);
    f4*       dst = (f4*)(out + (size_t)row * DD);
    for (int i = threadIdx.x; i < DD / 4; i += blockDim.x) dst[i] = src[i];
}

__global__ void k_copy_int(const int* __restrict__ src, int* __restrict__ dst, int n) {
    int i = blockIdx.x * blockDim.x + threadIdx.x;
    if (i < n) dst[i] = src[i];
}

// H[i] += sum_z P[z*len + i]
__global__ void k_addN(float* __restrict__ H, const float* __restrict__ P,
                       long len, int nparts) {
    long i = (long)blockIdx.x * 256 + threadIdx.x;
    if (i >= len / 4) return;
    f4 h = ((f4*)H)[i];
    for (int z = 0; z < nparts; z++) {
        f4 p = ((const f4*)(P + (size_t)z * len))[i];
        h.x += p.x; h.y += p.y; h.z += p.z; h.w += p.w;
    }
    ((f4*)H)[i] = h;
}

// ---------------- rmsnorm -> bf16 hi/lo planes ----------------
__global__ __launch_bounds__(256) void k_rmsnorm_cvt(const float* __restrict__ x,
                                                     const float* __restrict__ w,
                                                     u16* __restrict__ OH,
                                                     u16* __restrict__ OL) {
    int row = blockIdx.x;
    const float* xr = x + (size_t)row * DD;
    float ss = 0.f;
    for (int i = threadIdx.x; i < DD / 4; i += blockDim.x) {
        f4 v = ((const f4*)xr)[i];
        ss += v.x * v.x + v.y * v.y + v.z * v.z + v.w * v.w;
    }
    for (int o = 32; o > 0; o >>= 1) ss += __shfl_down(ss, o);
    __shared__ float red[4];
    int wid = threadIdx.x >> 6, lane = threadIdx.x & 63;
    if (lane == 0) red[wid] = ss;
    __syncthreads();
    float tot = red[0] + red[1] + red[2] + red[3];
    float inv = 1.0f / sqrtf(tot / (float)DD + 1e-6f);
    for (int i = threadIdx.x; i < DD / 4; i += blockDim.x) {
        f4 v = ((const f4*)xr)[i];
        f4 wv = ((const f4*)w)[i];
        float o[4];
        o[0] = v.x * wv.x * inv; o[1] = v.y * wv.y * inv;
        o[2] = v.z * wv.z * inv; o[3] = v.w * wv.w * inv;
        ushort4 hv, lv;
        u16* hp = (u16*)&hv; u16* lp = (u16*)&lv;
#pragma unroll
        for (int j = 0; j < 4; j++) {
            u16 h = bf16rne(o[j]);
            hp[j] = h;
            lp[j] = bf16rne(o[j] - bf16tof(h));
        }
        *(ushort4*)&OH[(size_t)row * DD + i * 4] = hv;
        *(ushort4*)&OL[(size_t)row * DD + i * 4] = lv;
    }
}

// ---------------- weight transpose+convert: W[K][N] -> planes [n][K] -------
__global__ __launch_bounds__(256) void k_cvt_w(const float* __restrict__ W,
                                               u16* __restrict__ WtH,
                                               u16* __restrict__ WtL,
                                               int K, int N, int nc0, int dn0,
                                               int writeLo) {
    __shared__ float T[64][65];
    int tid = threadIdx.x;
    int n0g = nc0 + blockIdx.x * 64;
    int k0  = blockIdx.y * 64;
#pragma unroll
    for (int it = 0; it < 4; it++) {
        int r = it * 16 + (tid >> 4);
        int c4 = (tid & 15) * 4;
        f4 v = *(const f4*)(W + (size_t)(k0 + r) * N + n0g + c4);
        T[r][c4 + 0] = v.x; T[r][c4 + 1] = v.y;
        T[r][c4 + 2] = v.z; T[r][c4 + 3] = v.w;
    }
    __syncthreads();
    int nl = tid >> 2;
    int ks = (tid & 3) * 16;
    u16 hi[16], lo[16];
#pragma unroll
    for (int j = 0; j < 16; j++) {
        float v = T[ks + j][nl];
        u16 h = bf16rne(v);
        hi[j] = h;
        lo[j] = bf16rne(v - bf16tof(h));
    }
    size_t base = (size_t)(dn0 + blockIdx.x * 64 + nl) * K + k0 + ks;
    *(short8*)&WtH[base]     = *(short8*)&hi[0];
    *(short8*)&WtH[base + 8] = *(short8*)&hi[8];
    if (writeLo) {
        *(short8*)&WtL[base]     = *(short8*)&lo[0];
        *(short8*)&WtL[base + 8] = *(short8*)&lo[8];
    }
}

// ---------------- bf16 MFMA GEMM, m97 structure (128x128) ----------------
template <int PASSES, int RES, int DUAL>
__global__ __launch_bounds__(256, 2) void k_bgemm(const u16* __restrict__ AH,
                                                  const u16* __restrict__ AL,
                                                  const u16* __restrict__ B1H,
                                                  const u16* __restrict__ B1L,
                                                  const u16* __restrict__ B2H,
                                                  const u16* __restrict__ B2L,
                                                  const float* __restrict__ Rsrc,
                                                  float* __restrict__ C,
                                                  u16* __restrict__ OH,
                                                  u16* __restrict__ OL,
                                                  int M, int ldC, int K) {
    constexpr int NW = DUAL ? 2 : 1;
    __shared__ u16 As[128 * 32];
    __shared__ u16 Bs[NW][128 * 32];
    int tid = threadIdx.x;
    int bx = blockIdx.x, by = blockIdx.y;
    xcd_swz(bx, by);
    int m0 = by * 128, n0 = bx * 128;
    int lane = tid & 63, w = tid >> 6;
    int wm = w >> 1, wn = w & 1;
    int lr = lane & 15, lq = lane >> 4;
    int grow = lane >> 2;
    int gcol = (lane & 3) * 8;

    f32x4 acc[NW][4][4];
#pragma unroll
    for (int u = 0; u < NW; u++)
#pragma unroll
        for (int i = 0; i < 4; i++)
#pragma unroll
            for (int j = 0; j < 4; j++)
#pragma unroll
                for (int r = 0; r < 4; r++) acc[u][i][j][r] = 0.f;

    const int KT = PASSES * K;
    for (int kb = 0; kb < KT; kb += 32) {
        int p  = (PASSES > 1) ? ((kb >= 2 * K) ? 2 : ((kb >= K) ? 1 : 0)) : 0;
        int ks = kb - p * K;
        const u16* Ab = ((p == 2) ? AL  : AH)  + (size_t)(m0 + w * 32) * K + ks;
        const u16* Bb = ((p == 1) ? B1L : B1H) + (size_t)(n0 + w * 32) * K + ks;
        __syncthreads();
        gload16(Ab + (size_t)grow * K + gcol,        &As[w * 1024]);
        gload16(Ab + (size_t)(grow + 16) * K + gcol, &As[w * 1024 + 512]);
        gload16(Bb + (size_t)grow * K + gcol,        &Bs[0][w * 1024]);
        gload16(Bb + (size_t)(grow + 16) * K + gcol, &Bs[0][w * 1024 + 512]);
        if constexpr (DUAL) {
            const u16* B2b = ((p == 1) ? B2L : B2H) + (size_t)(n0 + w * 32) * K + ks;
            gload16(B2b + (size_t)grow * K + gcol,        &Bs[1][w * 1024]);
            gload16(B2b + (size_t)(grow + 16) * K + gcol, &Bs[1][w * 1024 + 512]);
        }
        __syncthreads();
        short8 a[4];
#pragma unroll
        for (int i = 0; i < 4; i++)
            a[i] = *(const short8*)&As[(wm * 64 + i * 16 + lr) * 32 + lq * 8];
#pragma unroll
        for (int u = 0; u < NW; u++) {
#pragma unroll
            for (int j = 0; j < 4; j++) {
                short8 b = *(const short8*)&Bs[u][(wn * 64 + j * 16 + lr) * 32 + lq * 8];
#pragma unroll
                for (int i = 0; i < 4; i++)
                    acc[u][i][j] = __builtin_amdgcn_mfma_f32_16x16x32_bf16(
                        a[i], b, acc[u][i][j], 0, 0, 0);
            }
        }
    }
#pragma unroll
    for (int i = 0; i < 4; i++) {
#pragma unroll
        for (int j = 0; j < 4; j++) {
            int gm = m0 + wm * 64 + i * 16 + lq * 4;
            int gn = n0 + wn * 64 + j * 16 + lr;
#pragma unroll
            for (int r = 0; r < 4; r++) {
                size_t off = (size_t)(gm + r) * ldC + gn;
                if constexpr (DUAL) {
                    float g = acc[0][i][j][r], uu = acc[1][i][j][r];
                    float v = g / (1.0f + expf(-g)) * uu;
                    u16 h = bf16rne(v);
                    OH[off] = h;
                    OL[off] = bf16rne(v - bf16tof(h));
                } else {
                    float v = acc[0][i][j][r];
                    if constexpr (RES) v += Rsrc[off];
                    C[off] = v;
                }
            }
        }
    }
}

// ---------------- 256x256-tile GEMM, BK=32 / 4-buffer / counted vmcnt -------
// LDS: 4 buffers x (A[256][32] + B[256][32]) u16 = 4 x 32KB = 128KB.
// Chunk swizzle for 64B rows: phys chunk p of row r holds logical p^((r>>1)&3);
// writer via pre-swizzled source column (l&3)^((l>>3)&3); reader lq^((lr>>1)&3).
// EPI: epilogue reads gate planes GEH/GEL at off, v = silu(g) * acc (fp32 u).
template <int PASSES, int PLANE, int EPI>
__global__ __launch_bounds__(512, 2) void k_bg256(const u16* __restrict__ AH,
                                                  const u16* __restrict__ AL,
                                                  const u16* __restrict__ BH,
                                                  const u16* __restrict__ BL,
                                                  float* __restrict__ C,
                                                  u16* __restrict__ OH,
                                                  u16* __restrict__ OL,
                                                  const u16* __restrict__ GEH,
                                                  const u16* __restrict__ GEL,
                                                  int M, int ldC, int K, int ld) {
    __shared__ u16 SM[65536];
    int tid = threadIdx.x;
    int bx = blockIdx.x, by = blockIdx.y;
    xcd_swz(bx, by);
    {   // split-K part select
        size_t zo = (size_t)blockIdx.z * K;
        AH += zo; BH += zo;
        if constexpr (PASSES > 1) { AL += zo; BL += zo; }
        if constexpr (!PLANE) C += (size_t)blockIdx.z * ((size_t)M * ldC);
    }
    int m0 = by * 256, n0 = bx * 256;
    int w = tid >> 6, lane = tid & 63;
    int wm = w >> 2, wn = w & 3;
    int lr = lane & 15, lq = lane >> 4;
    int rc = (lq ^ ((lr >> 1) & 3)) * 8;   // swizzled read chunk

    f32x4 acc[8][4];
#pragma unroll
    for (int i = 0; i < 8; i++)
#pragma unroll
        for (int j = 0; j < 4; j++)
#pragma unroll
            for (int r = 0; r < 4; r++) acc[i][j][r] = 0.f;

    auto ASRC = [&](int T) -> const u16* {
        int kb = T * 32;
        if (PASSES > 1) {
            if (kb >= 2 * K) return AL + (kb - 2 * K);
            if (kb >= K)     return AH + (kb - K);
        }
        return AH + kb;
    };
    auto BSRC = [&](int T) -> const u16* {
        int kb = T * 32;
        if (PASSES > 1) {
            if (kb >= 2 * K) return BH + (kb - 2 * K);
            if (kb >= K)     return BL + (kb - K);
        }
        return BH + kb;
    };
    int srr = lane >> 2;                                   // 0..15
    int scc = (((lane & 3) ^ ((lane >> 3) & 3))) * 8;      // pre-swizzled src col
    // STAGE: wave w stages rows w*32..w*32+31 of both A and B (4 gloads/wave)
    auto STAGE = [&](int T, int buf) {
        const u16* sa = ASRC(T) + (size_t)(m0 + w * 32 + srr) * ld + scc;
        u16* da = SM + buf * 16384 + (w * 32) * 32;
        gload16(sa, da);
        gload16(sa + (size_t)16 * ld, da + 16 * 32);
        const u16* sb = BSRC(T) + (size_t)(n0 + w * 32 + srr) * ld + scc;
        u16* db = SM + buf * 16384 + 8192 + (w * 32) * 32;
        gload16(sb, db);
        gload16(sb + (size_t)16 * ld, db + 16 * 32);
    };

    const int NT = (PASSES * K) >> 5;
    STAGE(0, 0); STAGE(1, 1); STAGE(2, 2);
    asm volatile("s_waitcnt vmcnt(8)" ::: "memory");   // tile0 retired
    BARRIER();

    for (int T = 0; T < NT; T++) {
        const u16* Ab = SM + (T & 3) * 16384;
        const u16* Bb = Ab + 8192;
        short8 aF[8], bF[4];
#pragma unroll
        for (int i = 0; i < 8; i++) {
            int row = (i >> 2) * 128 + wm * 64 + (i & 3) * 16 + lr;
            aF[i] = *(const short8*)&Ab[row * 32 + rc];
        }
        if (T + 3 < NT) STAGE(T + 3, (T + 3) & 3);
#pragma unroll
        for (int j = 0; j < 4; j++) {
            int row = (j >> 1) * 128 + wn * 32 + (j & 1) * 16 + lr;
            bF[j] = *(const short8*)&Bb[row * 32 + rc];
        }
        __builtin_amdgcn_s_setprio(1);
#pragma unroll
        for (int j = 0; j < 4; j++)
#pragma unroll
            for (int i = 0; i < 8; i++)
                acc[i][j] = __builtin_amdgcn_mfma_f32_16x16x32_bf16(
                    aF[i], bF[j], acc[i][j], 0, 0, 0);
        __builtin_amdgcn_s_setprio(0);
        if (T + 1 < NT) {
            if (T + 3 < NT)      asm volatile("s_waitcnt vmcnt(8)" ::: "memory");
            else if (T + 2 < NT) asm volatile("s_waitcnt vmcnt(4)" ::: "memory");
            else                 asm volatile("s_waitcnt vmcnt(0)" ::: "memory");
            BARRIER();
        }
    }

#pragma unroll
    for (int i16 = 0; i16 < 8; i16++) {
#pragma unroll
        for (int jj = 0; jj < 4; jj++) {
            int gm = m0 + (i16 >> 2) * 128 + wm * 64 + (i16 & 3) * 16 + lq * 4;
            int gn = n0 + (jj >> 1) * 128 + wn * 32 + (jj & 1) * 16 + lr;
#pragma unroll
            for (int r = 0; r < 4; r++) {
                size_t off = (size_t)(gm + r) * ldC + gn;
                float v = acc[i16][jj][r];
                if constexpr (PLANE) {
                    if constexpr (EPI) {
                        float g = bf16tof(GEH[off]) + bf16tof(GEL[off]);
                        v = g / (1.0f + expf(-g)) * v;
                    }
                    u16 h = bf16rne(v);
                    OH[off] = h;
                    OL[off] = bf16rne(v - bf16tof(h));
                } else {
                    C[off] = v;
                }
            }
        }
    }
}

// ---------------- RoPE ----------------
__global__ void k_rope_table(float* __restrict__ cosT, float* __restrict__ sinT) {
    int idx = blockIdx.x * blockDim.x + threadIdx.x;
    if (idx >= SSEQ * 64) return;
    int pos = idx >> 6, d = idx & 63;
    float p   = (float)pow(10000.0, (double)d * (1.0 / 64.0));
    float inv = 1.0f / p;
    float ang = (float)pos * inv;
    cosT[idx] = (float)cos((double)ang);
    sinT[idx] = (float)sin((double)ang);
}

// tier-D only: in-place rotate Q,K of CQKV
__global__ void k_rope(float* __restrict__ C,
                       const float* __restrict__ cosT, const float* __restrict__ sinT,
                       int s, int ld) {
    int bi = blockIdx.x;
    int h = bi % HH;
    int i = (bi / HH) % s;
    size_t base = (size_t)(bi / HH) * ld + h * DHH;
    int d = threadIdx.x;
    float c  = cosT[i * 64 + d];
    float sn = sinT[i * 64 + d];
    float x1 = C[base + d], x2 = C[base + 64 + d];
    C[base + d]      = x1 * c - x2 * sn;
    C[base + 64 + d] = x1 * sn + x2 * c;
    x1 = C[base + 2048 + d]; x2 = C[base + 2048 + 64 + d];
    C[base + 2048 + d]      = x1 * c - x2 * sn;
    C[base + 2048 + 64 + d] = x1 * sn + x2 * c;
}

// ---------------- fused RoPE + Q/K fp32 -> bf16 hi/lo planes ----------------
__global__ __launch_bounds__(256) void k_cvt_qkr(const float* __restrict__ C,
                                                 const float* __restrict__ cosT,
                                                 const float* __restrict__ sinT,
                                                 u16* __restrict__ QHp, u16* __restrict__ QLp,
                                                 u16* __restrict__ KHp, u16* __restrict__ KLp,
                                                 int s) {
    int row = blockIdx.x;
    int i = row % s;
    int c = threadIdx.x * 8;
    int d = c & 127;
    int hi2 = (d >= 64) ? 1 : 0;
    int dd = d - hi2 * 64;
    const float* tb = cosT + (size_t)i * 64;
    const float* ts = sinT + (size_t)i * 64;
#pragma unroll
    for (int sec = 0; sec < 2; sec++) {
        const float* src = C + (size_t)row * 6144 + sec * 2048;
        int base1 = c - hi2 * 64;
        float o[8];
#pragma unroll
        for (int q = 0; q < 2; q++) {
            f4 v1 = *(const f4*)(src + base1 + q * 4);
            f4 v2 = *(const f4*)(src + base1 + 64 + q * 4);
            float a1[4] = {v1.x, v1.y, v1.z, v1.w};
            float a2[4] = {v2.x, v2.y, v2.z, v2.w};
#pragma unroll
            for (int e = 0; e < 4; e++) {
                float cc = tb[dd + q * 4 + e];
                float sn = ts[dd + q * 4 + e];
                o[q * 4 + e] = hi2 ? (a1[e] * sn + a2[e] * cc)
                                   : (a1[e] * cc - a2[e] * sn);
            }
        }
        u16 hbuf[8], lbuf[8];
#pragma unroll
        for (int e = 0; e < 8; e++) {
            u16 h = bf16rne(o[e]);
            hbuf[e] = h;
            lbuf[e] = bf16rne(o[e] - bf16tof(h));
        }
        u16* dh = (sec ? KHp : QHp) + (size_t)row * 2048 + c;
        u16* dl = (sec ? KLp : QLp) + (size_t)row * 2048 + c;
        *(short8*)dh = *(short8*)&hbuf[0];
        *(short8*)dl = *(short8*)&lbuf[0];
    }
}

// ---------------- V -> transposed swizzled planes Vt[b*h][128][s] ----------
__global__ __launch_bounds__(256) void k_cvt_vt(const float* __restrict__ C,
                                                u16* __restrict__ VtH,
                                                u16* __restrict__ VtL, int s) {
    __shared__ float T[64][132];
    int bh = blockIdx.y;
    int h = bh & 15, b = bh >> 4;
    int kv0 = blockIdx.x * 64;
    int t = threadIdx.x;
#pragma unroll
    for (int it = 0; it < 8; it++) {
        int kv = it * 8 + (t >> 5);
        int c4 = (t & 31) * 4;
        f4 v = *(const f4*)(C + (size_t)((size_t)b * s + kv0 + kv) * 6144 + 4096 + h * 128 + c4);
        T[kv][c4 + 0] = v.x; T[kv][c4 + 1] = v.y;
        T[kv][c4 + 2] = v.z; T[kv][c4 + 3] = v.w;
    }
    __syncthreads();
    int d = t >> 1, seg = t & 1;
    size_t base = ((size_t)bh * 128 + d) * s + kv0 + seg * 32;
#pragma unroll
    for (int g = 0; g < 4; g++) {
        u16 h8[8], l8[8];
#pragma unroll
        for (int e = 0; e < 8; e++) {
            float v = T[seg * 32 + g * 8 + e][d];
            u16 hh = bf16rne(v);
            h8[e] = hh;
            l8[e] = bf16rne(v - bf16tof(hh));
        }
        int gp = (g ^ ((d >> 1) & 3)) * 8;
        *(short8*)&VtH[base + gp] = *(short8*)&h8[0];
        *(short8*)&VtL[base + gp] = *(short8*)&l8[0];
    }
}

// ---------------- MFMA flash attention (QBLK=128, pipelined, bh-chunked) ----
template <int PASSES>
__global__ __launch_bounds__(256, 2) void k_attn_mfma(
        const u16* __restrict__ QHp, const u16* __restrict__ QLp,
        const u16* __restrict__ KHp, const u16* __restrict__ KLp,
        const u16* __restrict__ VtH, const u16* __restrict__ VtL,
        const int* __restrict__ mask,
        u16* __restrict__ OH, u16* __restrict__ OL, int s) {
    constexpr int BUFU = (PASSES > 1) ? 16384 : 8192;
    constexpr int VOFF = (PASSES > 1) ? 8192 : 4096;
    __shared__ u16 SM[2 * BUFU + 5120];
    int tid = threadIdx.x, lane = tid & 63, w = tid >> 6;
    int lr = lane & 15, lq = lane >> 4;
    int grow = lane >> 2;
    int sgcol = (((lane & 3) ^ ((lane >> 3) & 3))) * 8;
    int gcol  = (lane & 3) * 8;
    int rc = (lq ^ ((lr >> 1) & 3)) * 8;
    int gx = gridDim.x;
    int NB = gx * gridDim.y;
    int orig = blockIdx.y * gx + blockIdx.x;
    int qq = NB >> 3, rr = NB & 7;
    int xcd = orig & 7, loc = orig >> 3;
    int swz = (xcd < rr ? xcd * (qq + 1) : rr * (qq + 1) + (xcd - rr) * qq) + loc;
    int bh = swz / gx;
    int qt = gx - 1 - (swz % gx);
    int h = bh & 15, b = bh >> 4;
    int q0 = qt * 128;
    size_t rb = (size_t)b * s;
    const u16* vtH = VtH + (size_t)bh * 128 * s;
    const u16* vtL = VtL + (size_t)bh * 128 * s;
    u16* PHw = SM + 2 * BUFU + w * 1280;
    u16* PLw = PHw + 640;
    const float scale = 0.08838834764831845f;

    short8 qh[2][4], ql[2][4];
#pragma unroll
    for (int st = 0; st < 2; st++) {
        const u16* qp = QHp + (rb + q0 + st * 64) * 2048 + h * 128 + w * 32;
#pragma unroll
        for (int it = 0; it < 4; it++)
            gload16(qp + (size_t)(it * 16 + grow) * 2048 + sgcol, SM + w * 2048 + it * 512);
        __syncthreads();
#pragma unroll
        for (int ks = 0; ks < 4; ks++)
            qh[st][ks] = *(const short8*)&SM[ks * 2048 + (w * 16 + lr) * 32 + rc];
        if constexpr (PASSES > 1) {
            __syncthreads();
            const u16* qp2 = QLp + (rb + q0 + st * 64) * 2048 + h * 128 + w * 32;
#pragma unroll
            for (int it = 0; it < 4; it++)
                gload16(qp2 + (size_t)(it * 16 + grow) * 2048 + sgcol, SM + w * 2048 + it * 512);
            __syncthreads();
#pragma unroll
            for (int ks = 0; ks < 4; ks++)
                ql[st][ks] = *(const short8*)&SM[ks * 2048 + (w * 16 + lr) * 32 + rc];
        }
        __syncthreads();
    }

    auto kv_stage = [&](int t, int buf) {
        u16* base = SM + buf * BUFU;
        const u16* kp = KHp + (rb + t * 32) * 2048 + h * 128 + w * 32;
        gload16(kp + (size_t)grow * 2048 + sgcol,        base + w * 1024);
        gload16(kp + (size_t)(16 + grow) * 2048 + sgcol, base + w * 1024 + 512);
        const u16* vp = vtH + (size_t)(w * 32) * s + t * 32;
        gload16(vp + (size_t)grow * s + gcol,        base + VOFF + (w * 32) * 32);
        gload16(vp + (size_t)(16 + grow) * s + gcol, base + VOFF + (w * 32 + 16) * 32);
        if constexpr (PASSES > 1) {
            const u16* kp2 = KLp + (rb + t * 32) * 2048 + h * 128 + w * 32;
            gload16(kp2 + (size_t)grow * 2048 + sgcol,        base + 4096 + w * 1024);
            gload16(kp2 + (size_t)(16 + grow) * 2048 + sgcol, base + 4096 + w * 1024 + 512);
            const u16* vp2 = vtL + (size_t)(w * 32) * s + t * 32;
            gload16(vp2 + (size_t)grow * s + gcol,        base + 12288 + (w * 32) * 32);
            gload16(vp2 + (size_t)(16 + grow) * s + gcol, base + 12288 + (w * 32 + 16) * 32);
        }
    };

    f32x4 o_acc[2][8];
#pragma unroll
    for (int st = 0; st < 2; st++)
#pragma unroll
        for (int j = 0; j < 8; j++)
#pragma unroll
            for (int r = 0; r < 4; r++) o_acc[st][j][r] = 0.f;
    float m_run[2][4], l_run[2][4];
#pragma unroll
    for (int st = 0; st < 2; st++)
#pragma unroll
        for (int r = 0; r < 4; r++) { m_run[st][r] = -3.0e38f; l_run[st][r] = 0.f; }

    int nt = (q0 + 128) >> 5;
    int mv0 = mask[rb + lr];
    int mv1 = mask[rb + 16 + lr];
    kv_stage(0, 0);
    for (int t = 0; t < nt; t++) {
        int bsel = t & 1;
        if (t + 1 < nt) {
            kv_stage(t + 1, 1 - bsel);
            if constexpr (PASSES > 1)
                asm volatile("s_waitcnt vmcnt(8)" ::: "memory");
            else
                asm volatile("s_waitcnt vmcnt(4)" ::: "memory");
        } else {
            asm volatile("s_waitcnt vmcnt(0)" ::: "memory");
        }
        BARRIER();
        int nmv0 = mv0, nmv1 = mv1;
        if (t + 1 < nt) {
            nmv0 = mask[rb + (t + 1) * 32 + lr];
            nmv1 = mask[rb + (t + 1) * 32 + 16 + lr];
        }
        const u16* KsH = SM + bsel * BUFU;
        const u16* KsL = KsH + 4096;
        const u16* VsH = SM + bsel * BUFU + VOFF;
        const u16* VsL = SM + bsel * BUFU + 12288;
#pragma unroll
        for (int st = 0; st < 2; st++) {
            if (t * 32 > q0 + st * 64 + w * 16 + 15) continue;
            f32x4 sa[2];
#pragma unroll
            for (int j = 0; j < 2; j++)
#pragma unroll
                for (int r = 0; r < 4; r++) sa[j][r] = 0.f;
#pragma unroll
            for (int j = 0; j < 2; j++) {
#pragma unroll
                for (int ks = 0; ks < 4; ks++) {
                    short8 kb = *(const short8*)&KsH[ks * 1024 + (j * 16 + lr) * 32 + rc];
                    sa[j] = __builtin_amdgcn_mfma_f32_16x16x32_bf16(qh[st][ks], kb, sa[j], 0, 0, 0);
                    if constexpr (PASSES > 1) {
                        short8 kl2 = *(const short8*)&KsL[ks * 1024 + (j * 16 + lr) * 32 + rc];
                        sa[j] = __builtin_amdgcn_mfma_f32_16x16x32_bf16(qh[st][ks], kl2, sa[j], 0, 0, 0);
                        sa[j] = __builtin_amdgcn_mfma_f32_16x16x32_bf16(ql[st][ks], kb, sa[j], 0, 0, 0);
                    }
                }
            }
            float sclv[4];
#pragma unroll
            for (int r = 0; r < 4; r++) {
                int ig = q0 + st * 64 + w * 16 + lq * 4 + r;
                float v0 = (t * 32 + lr <= ig && mv0 > 0) ? sa[0][r] * scale : -1.0e9f;
                float v1 = (t * 32 + 16 + lr <= ig && mv1 > 0) ? sa[1][r] * scale : -1.0e9f;
                float mx = fmaxf(v0, v1);
                mx = fmaxf(mx, __shfl_xor(mx, 1));
                mx = fmaxf(mx, __shfl_xor(mx, 2));
                mx = fmaxf(mx, __shfl_xor(mx, 4));
                mx = fmaxf(mx, __shfl_xor(mx, 8));
                float mo = m_run[st][r];
                float mn = fmaxf(mo, mx);
                float p0 = expf(v0 - mn), p1 = expf(v1 - mn);
                float ps = p0 + p1;
                ps += __shfl_xor(ps, 1);
                ps += __shfl_xor(ps, 2);
                ps += __shfl_xor(ps, 4);
                ps += __shfl_xor(ps, 8);
                sclv[r] = expf(mo - mn);
                m_run[st][r] = mn;
                l_run[st][r] = l_run[st][r] * sclv[r] + ps;
                int prow = lq * 4 + r;
                u16 h0 = bf16rne(p0);
                u16 h1 = bf16rne(p1);
                PHw[prow * 40 + lr] = h0;
                PHw[prow * 40 + 16 + lr] = h1;
                if constexpr (PASSES > 1) {
                    PLw[prow * 40 + lr] = bf16rne(p0 - bf16tof(h0));
                    PLw[prow * 40 + 16 + lr] = bf16rne(p1 - bf16tof(h1));
                }
            }
#pragma unroll
            for (int j = 0; j < 8; j++)
#pragma unroll
                for (int r = 0; r < 4; r++) o_acc[st][j][r] *= sclv[r];
            short8 ph = *(const short8*)&PHw[lr * 40 + lq * 8];
            short8 pl;
            if constexpr (PASSES > 1) pl = *(const short8*)&PLw[lr * 40 + lq * 8];
#pragma unroll
            for (int j = 0; j < 8; j++) {
                int vrow = j * 16 + lr;
                short8 vh = *(const short8*)&VsH[vrow * 32 + rc];
                o_acc[st][j] = __builtin_amdgcn_mfma_f32_16x16x32_bf16(ph, vh, o_acc[st][j], 0, 0, 0);
                if constexpr (PASSES > 1) {
                    short8 vl = *(const short8*)&VsL[vrow * 32 + rc];
                    o_acc[st][j] = __builtin_amdgcn_mfma_f32_16x16x32_bf16(ph, vl, o_acc[st][j], 0, 0, 0);
                    o_acc[st][j] = __builtin_amdgcn_mfma_f32_16x16x32_bf16(pl, vh, o_acc[st][j], 0, 0, 0);
                }
            }
        }
        BARRIER();
        mv0 = nmv0; mv1 = nmv1;
    }
#pragma unroll
    for (int st = 0; st < 2; st++) {
#pragma unroll
        for (int r = 0; r < 4; r++) {
            float linv = 1.0f / l_run[st][r];
            size_t rowoff = (rb + q0 + st * 64 + w * 16 + lq * 4 + r) * 2048 + h * 128 + lr;
#pragma unroll
            for (int j = 0; j < 8; j++) {
                float v = o_acc[st][j][r] * linv;
                u16 hh = bf16rne(v);
                OH[rowoff + j * 16] = hh;
                OL[rowoff + j * 16] = bf16rne(v - bf16tof(hh));
            }
        }
    }
}

// ---------------- fp32 flash attention (tier D fallback) ----------------
__global__ __launch_bounds__(256, 2) void k_attn_f32(const float* __restrict__ Q,
                                                     const float* __restrict__ K,
                                                     const float* __restrict__ V,
                                                     const int* __restrict__ mask,
                                                     u16* __restrict__ OH,
                                                     u16* __restrict__ OL, int s, int ld) {
    int qt = blockIdx.x, bh = blockIdx.y;
    int h = bh & (HH - 1), b = bh >> 4;
    __shared__ float Qs[64][132];
    __shared__ float Ks[32 * 128];
    __shared__ float Vs[32][132];
    __shared__ float Ps[64][36];
    __shared__ float mrow[64], lrow[64];
    int tid = threadIdx.x;
    int tx = tid & 15, ty = tid >> 4;

#pragma unroll
    for (int p = 0; p < 2; p++) {
        int r = p * 32 + (tid >> 3);
        int kb = (tid & 7) * 4;
        const float* src = Q + (size_t)(b * s + qt * 64 + r) * ld + h * DHH;
#pragma unroll
        for (int q = 0; q < 4; q++)
            *(f4*)&Qs[r][kb + 32 * q] = *(const f4*)(src + kb + 32 * q);
    }
    if (tid < 64) { mrow[tid] = -3.0e38f; lrow[tid] = 0.f; }

    float acc[4][8];
#pragma unroll
    for (int i = 0; i < 4; i++)
#pragma unroll
        for (int c = 0; c < 8; c++) acc[i][c] = 0.f;
    const float scale = 0.08838834764831845f;

    int ktmax = 2 * (qt + 1);
    for (int kt = 0; kt < ktmax; kt++) {
        __syncthreads();
#pragma unroll
        for (int p = 0; p < 4; p++) {
            int c = p * 8 + (tid >> 5);
            int kk = (tid & 31) * 4;
            size_t g = (size_t)(b * s + kt * 32 + c) * ld + h * DHH + kk;
            f4 kv = *(const f4*)(K + g);
            int ch = (kk >> 2) ^ (c >> 1);
            *(f4*)&Ks[c * 128 + ch * 4] = kv;
            *(f4*)&Vs[c][kk] = *(const f4*)(V + g);
        }
        __syncthreads();
        float sv[4][2];
#pragma unroll
        for (int i = 0; i < 4; i++) { sv[i][0] = 0.f; sv[i][1] = 0.f; }
        for (int kk = 0; kk < 128; kk += 4) {
            f4 qv[4];
#pragma unroll
            for (int i = 0; i < 4; i++) qv[i] = *(const f4*)&Qs[ty * 4 + i][kk];
#pragma unroll
            for (int j = 0; j < 2; j++) {
                int c = tx * 2 + j;
                int ch = (kk >> 2) ^ (c >> 1);
                f4 kv = *(const f4*)&Ks[c * 128 + ch * 4];
#pragma unroll
                for (int i = 0; i < 4; i++)
                    sv[i][j] += qv[i].x * kv.x + qv[i].y * kv.y +
                                qv[i].z * kv.z + qv[i].w * kv.w;
            }
        }
        float scl[4];
#pragma unroll
        for (int i = 0; i < 4; i++) {
            int r = ty * 4 + i;
            int igl = qt * 64 + r;
#pragma unroll
            for (int j = 0; j < 2; j++) {
                int jg = kt * 32 + tx * 2 + j;
                bool ok = (jg <= igl) && (mask[b * s + jg] > 0);
                sv[i][j] = ok ? sv[i][j] * scale : -1.0e9f;
            }
            float rmax = fmaxf(sv[i][0], sv[i][1]);
            rmax = fmaxf(rmax, __shfl_xor(rmax, 1));
            rmax = fmaxf(rmax, __shfl_xor(rmax, 2));
            rmax = fmaxf(rmax, __shfl_xor(rmax, 4));
            rmax = fmaxf(rmax, __shfl_xor(rmax, 8));
            float mold = mrow[r];
            float mnew = fmaxf(mold, rmax);
            float p0 = expf(sv[i][0] - mnew);
            float p1 = expf(sv[i][1] - mnew);
            float ps = p0 + p1;
            ps += __shfl_xor(ps, 1);
            ps += __shfl_xor(ps, 2);
            ps += __shfl_xor(ps, 4);
            ps += __shfl_xor(ps, 8);
            scl[i] = expf(mold - mnew);
            if (tx == 0) { mrow[r] = mnew; lrow[r] = lrow[r] * scl[i] + ps; }
            float2 pw; pw.x = p0; pw.y = p1;
            *(float2*)&Ps[r][tx * 2] = pw;
        }
        __syncthreads();
#pragma unroll
        for (int i = 0; i < 4; i++) {
            float sc = scl[i];
#pragma unroll
            for (int c = 0; c < 8; c++) acc[i][c] *= sc;
        }
        for (int jj = 0; jj < 32; jj += 4) {
            f4 pv[4];
#pragma unroll
            for (int i = 0; i < 4; i++) pv[i] = *(const f4*)&Ps[ty * 4 + i][jj];
#pragma unroll
            for (int j2 = 0; j2 < 4; j2++) {
                f4 va = *(const f4*)&Vs[jj + j2][tx * 4];
                f4 vb = *(const f4*)&Vs[jj + j2][64 + tx * 4];
#pragma unroll
                for (int i = 0; i < 4; i++) {
                    float p = (&pv[i].x)[j2];
                    acc[i][0] += p * va.x; acc[i][1] += p * va.y;
                    acc[i][2] += p * va.z; acc[i][3] += p * va.w;
                    acc[i][4] += p * vb.x; acc[i][5] += p * vb.y;
                    acc[i][6] += p * vb.z; acc[i][7] += p * vb.w;
                }
            }
        }
    }
    __syncthreads();
#pragma unroll
    for (int i = 0; i < 4; i++) {
        int r = ty * 4 + i;
        float linv = 1.0f / lrow[r];
        size_t ob = (size_t)(b * s + qt * 64 + r) * DD + h * DHH;
        ushort4 h1, l1, h2, l2;
        u16 *h1p = (u16*)&h1, *l1p = (u16*)&l1, *h2p = (u16*)&h2, *l2p = (u16*)&l2;
#pragma unroll
        for (int c = 0; c < 4; c++) {
            float v = acc[i][c] * linv;
            u16 hh = bf16rne(v);
            h1p[c] = hh; l1p[c] = bf16rne(v - bf16tof(hh));
            float v2 = acc[i][c + 4] * linv;
            u16 hh2 = bf16rne(v2);
            h2p[c] = hh2; l2p[c] = bf16rne(v2 - bf16tof(hh2));
        }
        *(ushort4*)&OH[ob + tx * 4] = h1;
        *(ushort4*)&OL[ob + tx * 4] = l1;
        *(ushort4*)&OH[ob + 64 + tx * 4] = h2;
        *(ushort4*)&OL[ob + 64 + tx * 4] = l2;
    }
}

// ---------------- prune scoring / selection ----------------
__global__ __launch_bounds__(256) void k_score(const float* __restrict__ Hb,
                                               const float* __restrict__ srow,
                                               float* __restrict__ sc) {
    int row = blockIdx.x;
    const float* xr = Hb + (size_t)row * DD;
    float ss = 0.f;
    for (int i = threadIdx.x; i < DD / 4; i += blockDim.x) {
        f4 a = ((const f4*)xr)[i];
        f4 w = ((const f4*)srow)[i];
        ss += a.x * w.x + a.y * w.y + a.z * w.z + a.w * w.w;
    }
    for (int o = 32; o > 0; o >>= 1) ss += __shfl_down(ss, o);
    __shared__ float red[4];
    int wid = threadIdx.x >> 6, lane = threadIdx.x & 63;
    if (lane == 0) red[wid] = ss;
    __syncthreads();
    if (threadIdx.x == 0) sc[row] = red[0] + red[1] + red[2] + red[3];
}

__global__ __launch_bounds__(256) void k_rank(const float* __restrict__ sc,
                                              int* __restrict__ flg, int s, int kk) {
    int b = blockIdx.x / s, i = blockIdx.x % s;
    const float* scb = sc + (size_t)b * s;
    float vi = scb[i];
    int cnt = 0;
    for (int j = threadIdx.x; j < s; j += 256) {
        float vj = scb[j];
        if (vj > vi || (vj == vi && j < i)) cnt++;
    }
    for (int o = 32; o > 0; o >>= 1) cnt += __shfl_down(cnt, o);
    __shared__ int red[4];
    int wid = threadIdx.x >> 6, lane = threadIdx.x & 63;
    if (lane == 0) red[wid] = cnt;
    __syncthreads();
    if (threadIdx.x == 0) flg[b * s + i] = ((red[0] + red[1] + red[2] + red[3]) < kk) ? 1 : 0;
}

__global__ void k_compact(const int* __restrict__ flg, int* __restrict__ idx, int s, int kk) {
    int b = blockIdx.x;
    if (threadIdx.x == 0) {
        int p = 0;
        for (int i = 0; i < s; i++)
            if (flg[b * s + i]) idx[b * kk + (p++)] = i;
    }
}

__global__ void k_gather(const float* __restrict__ Hin, const int* __restrict__ idx,
                         float* __restrict__ Hout, int s, int kk) {
    int row = blockIdx.x;
    int b = row / kk, p = row % kk;
    int i = idx[b * kk + p];
    const f4* src = (const f4*)(Hin + (size_t)(b * s + i) * DD);
    f4* dst = (f4*)(Hout + (size_t)row * DD);
    for (int t = threadIdx.x; t < DD / 4; t += blockDim.x) dst[t] = src[t];
}

__global__ void k_gather_mask(const int* __restrict__ Min, const int* __restrict__ idx,
                              int* __restrict__ Mout, int s, int kk) {
    int t = blockIdx.x * blockDim.x + threadIdx.x;
    if (t < BBATCH * kk) {
        int b = t / kk, p = t % kk;
        Mout[t] = Min[b * s + idx[b * kk + p]];
    }
}

// ---------------------------------------------------------------------------
extern "C" void kernel_launch(void* const* d_in, const int* in_sizes, int n_in,
                              void* d_out, int out_size, void* d_ws, size_t ws_size,
                              hipStream_t stream) {
    const int*   input_ids = (const int*)d_in[0];
    const int*   attn_mask = (const int*)d_in[1];
    const float* embed     = (const float*)d_in[2];
    const float* wq        = (const float*)d_in[3];
    const float* wk        = (const float*)d_in[4];
    const float* wv        = (const float*)d_in[5];
    const float* wo        = (const float*)d_in[6];
    const float* wg        = (const float*)d_in[7];
    const float* wu        = (const float*)d_in[8];
    const float* wd        = (const float*)d_in[9];
    const float* ln1       = (const float*)d_in[10];
    const float* ln2       = (const float*)d_in[11];
    const float* lnf       = (const float*)d_in[12];
    const float* lm_head   = (const float*)d_in[13];
    const float* scorer    = (const float*)d_in[14];

    float* ws = (float*)d_ws;
    const size_t R = (size_t)BBATCH * SSEQ * DD;
    const size_t MISC_FLOATS = 2 * SSEQ * 64 + 5 * (size_t)BBATCH * SSEQ + 1024;
    const size_t NEED_A = (14 * R + MISC_FLOATS) * 4;
    const bool bigws = (ws_size >= NEED_A);

    float* H0   = ws;
    float* H1   = ws + R;
    float* CQKV = ws + 2 * R;
    u16*   AH   = (u16*)(ws + 5 * R);
    u16*   AL   = AH + (size_t)4096 * DD;

    u16* QHp = (u16*)(ws + 6 * R);
    u16* QLp = QHp + (size_t)4096 * DD;
    u16* KHp = (u16*)(ws + 7 * R);
    u16* KLp = KHp + (size_t)4096 * DD;
    u16* VtH = (u16*)(ws + 8 * R);
    u16* VtL = VtH + (size_t)4096 * DD;
    u16* FH  = (u16*)(ws + 6 * R);
    u16* FL  = (u16*)(ws + 8 * R);
    u16* WH1 = (u16*)(ws + 10 * R);
    u16* WL1 = WH1 + (size_t)FFF * DD;
    u16* WH2 = (u16*)(ws + 12 * R);
    u16* WL2 = WH2 + (size_t)FFF * DD;
    u16* WDH = (u16*)(ws + 10 * R);
    u16* WDL = WDH + (size_t)DD * FFF;
    u16* WQKVH = (u16*)(ws + 10 * R);
    u16* WQKVL = WQKVH + (size_t)6144 * DD;

    u16* cWgH = (u16*)CQKV;
    u16* cWgL = cWgH + (size_t)2048 * DD;
    u16* cWuH = cWgL + (size_t)2048 * DD;
    u16* cWuL = cWuH + (size_t)2048 * DD;
    u16* cFH  = (u16*)(ws + 3 * R);
    u16* cFL  = cFH + (size_t)4096 * 2048;
    u16* cWdH = (u16*)(ws + 4 * R);
    u16* cWdL = cWdH + (size_t)2048 * DD;

    float* miscB = ws + (bigws ? 14 * R : 6 * R);
    float* COS = miscB;
    float* SIN = COS + SSEQ * 64;
    float* SC  = SIN + SSEQ * 64;
    int*   FLG = (int*)(SC + (size_t)BBATCH * SSEQ);
    int*   IDX = FLG + BBATCH * SSEQ;
    int*   M0  = IDX + BBATCH * SSEQ;
    int*   M1  = M0 + BBATCH * SSEQ;

    k_rope_table<<<(SSEQ * 64 + 255) / 256, 256, 0, stream>>>(COS, SIN);
    k_embed<<<BBATCH * SSEQ, 256, 0, stream>>>(input_ids, embed, H0);
    k_copy_int<<<(BBATCH * SSEQ + 255) / 256, 256, 0, stream>>>(attn_mask, M0, BBATCH * SSEQ);

    float* Hc = H0; float* Nc = H1;
    int*   Mc = M0; int*   Mt = M1;
    int s = SSEQ;

    for (int l = 0; l < LLAYERS; l++) {
        if (l == 1 || l == 2) {
            int pi = l - 1;
            int kk = s / 2;
            k_score<<<BBATCH * s, 256, 0, stream>>>(Hc, scorer + (size_t)pi * 2 * DD, SC);
            k_rank<<<BBATCH * s, 256, 0, stream>>>(SC, FLG, s, kk);
            k_compact<<<BBATCH, 64, 0, stream>>>(FLG, IDX, s, kk);
            k_gather<<<BBATCH * kk, 256, 0, stream>>>(Hc, IDX, Nc, s, kk);
            k_gather_mask<<<(BBATCH * kk + 255) / 256, 256, 0, stream>>>(Mc, IDX, Mt, s, kk);
            { float* t = Hc; Hc = Nc; Nc = t; }
            { int* t = Mc; Mc = Mt; Mt = t; }
            s = kk;
        }
        int rows = BBATCH * s;
        const bool hiP = (l < 2);
        const int wlo = hiP ? 1 : 0;
        const float* Wq = wq + (size_t)l * DD * DD;
        const float* Wk = wk + (size_t)l * DD * DD;
        const float* Wv = wv + (size_t)l * DD * DD;
        const float* Wo = wo + (size_t)l * DD * DD;
        const float* Wg = wg + (size_t)l * DD * FFF;
        const float* Wu = wu + (size_t)l * DD * FFF;
        const float* Wd = wd + (size_t)l * FFF * DD;
        const float* L1 = ln1 + (size_t)l * DD;
        const float* L2 = ln2 + (size_t)l * DD;

        dim3 gWd(DD / 64, DD / 64);

        // ---- QKV projection (fused) ----
        k_rmsnorm_cvt<<<rows, 256, 0, stream>>>(Hc, L1, AH, AL);
        if (bigws) {
            k_cvt_w<<<gWd, 256, 0, stream>>>(Wq, WQKVH, WQKVL, DD, DD, 0, 0, wlo);
            k_cvt_w<<<gWd, 256, 0, stream>>>(Wk, WQKVH, WQKVL, DD, DD, 0, 2048, wlo);
            k_cvt_w<<<gWd, 256, 0, stream>>>(Wv, WQKVH, WQKVL, DD, DD, 0, 4096, wlo);
            if (rows >= 2048) {
                dim3 gQKV(6144 / 256, rows / 256);
                if (hiP) k_bg256<3,0,0><<<gQKV,512,0,stream>>>(AH,AL,WQKVH,WQKVL,CQKV,nullptr,nullptr,nullptr,nullptr,rows,6144,DD,DD);
                else     k_bg256<1,0,0><<<gQKV,512,0,stream>>>(AH,AL,WQKVH,WQKVL,CQKV,nullptr,nullptr,nullptr,nullptr,rows,6144,DD,DD);
            } else {
                dim3 gQKV(6144 / 128, rows / 128);
                k_bgemm<1,0,0><<<gQKV,256,0,stream>>>(AH,AL,WQKVH,WQKVL,nullptr,nullptr,nullptr,CQKV,nullptr,nullptr,rows,6144,DD);
            }
        } else {
            u16* WtH = (u16*)Nc;
            u16* WtL = WtH + (size_t)DD * DD;
            dim3 gG(DD / 128, rows / 128);
            const float* Wqkv[3] = {Wq, Wk, Wv};
            for (int q3 = 0; q3 < 3; q3++) {
                k_cvt_w<<<gWd, 256, 0, stream>>>(Wqkv[q3], WtH, WtL, DD, DD, 0, 0, wlo);
                float* Cb = CQKV + q3 * 2048;
                if (hiP) k_bgemm<3,0,0><<<gG,256,0,stream>>>(AH,AL,WtH,WtL,nullptr,nullptr,nullptr,Cb,nullptr,nullptr,rows,6144,DD);
                else     k_bgemm<1,0,0><<<gG,256,0,stream>>>(AH,AL,WtH,WtL,nullptr,nullptr,nullptr,Cb,nullptr,nullptr,rows,6144,DD);
            }
        }

        // ---- attention ----
        if (bigws) {
            k_cvt_qkr<<<rows, 256, 0, stream>>>(CQKV, COS, SIN, QHp, QLp, KHp, KLp, s);
            k_cvt_vt<<<dim3(s / 64, BBATCH * HH), 256, 0, stream>>>(CQKV, VtH, VtL, s);
            if (hiP) k_attn_mfma<3><<<dim3(s / 128, BBATCH * HH), 256, 0, stream>>>(
                         QHp, QLp, KHp, KLp, VtH, VtL, Mc, AH, AL, s);
            else     k_attn_mfma<1><<<dim3(s / 128, BBATCH * HH), 256, 0, stream>>>(
                         QHp, QLp, KHp, KLp, VtH, VtL, Mc, AH, AL, s);
        } else {
            k_rope<<<rows * HH, 64, 0, stream>>>(CQKV, COS, SIN, s, 6144);
            k_attn_f32<<<dim3(s / 64, BBATCH * HH), 256, 0, stream>>>(
                CQKV, CQKV + 2048, CQKV + 4096, Mc, AH, AL, s, 6144);
        }

        // ---- wo projection + residual ----
        {
            u16* WtH = bigws ? WQKVH : (u16*)Nc;
            u16* WtL = bigws ? (WQKVH + (size_t)DD * DD) : ((u16*)Nc + (size_t)DD * DD);
            k_cvt_w<<<gWd, 256, 0, stream>>>(Wo, WtH, WtL, DD, DD, 0, 0, wlo);
            if (bigws && hiP) {
                int SK = (rows >= 4096) ? 2 : 4;
                float* P = ws + 2 * R;
                dim3 g(DD / 256, rows / 256, SK);
                k_bg256<3,0,0><<<g, 512, 0, stream>>>(AH, AL, WtH, WtL, P,
                                                      nullptr, nullptr, nullptr, nullptr,
                                                      rows, DD, DD / SK, DD);
                long len = (long)rows * DD;
                k_addN<<<(len / 4 + 255) / 256, 256, 0, stream>>>(Hc, P, len, SK);
            } else {
                dim3 gG(DD / 128, rows / 128);
                if (hiP) k_bgemm<3,1,0><<<gG,256,0,stream>>>(AH,AL,WtH,WtL,nullptr,nullptr,Hc,Hc,nullptr,nullptr,rows,DD,DD);
                else     k_bgemm<1,1,0><<<gG,256,0,stream>>>(AH,AL,WtH,WtL,nullptr,nullptr,Hc,Hc,nullptr,nullptr,rows,DD,DD);
            }
        }

        // ---- MLP ----
        k_rmsnorm_cvt<<<rows, 256, 0, stream>>>(Hc, L2, AH, AL);
        if (bigws && rows >= 2048) {
            k_cvt_w<<<dim3(FFF / 64, DD / 64), 256, 0, stream>>>(Wg, WH1, WL1, DD, FFF, 0, 0, wlo);
            k_cvt_w<<<dim3(FFF / 64, DD / 64), 256, 0, stream>>>(Wu, WH2, WL2, DD, FFF, 0, 0, wlo);
            u16* Gh = (l == 0) ? (u16*)(ws + R) : (u16*)(ws + 2 * R);
            u16* Gl = (u16*)(ws + 3 * R);
            dim3 gMLP(FFF / 256, rows / 256);
            if (hiP) {
                k_bg256<3,1,0><<<gMLP,512,0,stream>>>(AH,AL,WH1,WL1,nullptr,Gh,Gl,nullptr,nullptr,rows,FFF,DD,DD);
                k_bg256<3,1,1><<<gMLP,512,0,stream>>>(AH,AL,WH2,WL2,nullptr,FH,FL,Gh,Gl,rows,FFF,DD,DD);
            } else {
                k_bg256<1,1,0><<<gMLP,512,0,stream>>>(AH,AL,WH1,WL1,nullptr,Gh,Gl,nullptr,nullptr,rows,FFF,DD,DD);
                k_bg256<1,1,1><<<gMLP,512,0,stream>>>(AH,AL,WH2,WL2,nullptr,FH,FL,Gh,Gl,rows,FFF,DD,DD);
            }
            k_cvt_w<<<dim3(DD / 64, FFF / 64), 256, 0, stream>>>(Wd, WDH, WDL, FFF, DD, 0, 0, wlo);
            int SK = (rows >= 4096) ? 2 : 4;
            float* P = ws + 2 * R;
            dim3 gD(DD / 256, rows / 256, SK);
            if (hiP) k_bg256<3,0,0><<<gD,512,0,stream>>>(FH,FL,WDH,WDL,P,nullptr,nullptr,nullptr,nullptr,rows,DD,FFF/SK,FFF);
            else     k_bg256<1,0,0><<<gD,512,0,stream>>>(FH,FL,WDH,WDL,P,nullptr,nullptr,nullptr,nullptr,rows,DD,FFF/SK,FFF);
            long len = (long)rows * DD;
            k_addN<<<(len / 4 + 255) / 256, 256, 0, stream>>>(Hc, P, len, SK);
        } else if (bigws) {
            k_cvt_w<<<dim3(FFF / 64, DD / 64), 256, 0, stream>>>(Wg, WH1, WL1, DD, FFF, 0, 0, wlo);
            k_cvt_w<<<dim3(FFF / 64, DD / 64), 256, 0, stream>>>(Wu, WH2, WL2, DD, FFF, 0, 0, wlo);
            k_bgemm<1,0,1><<<dim3(FFF/128, rows/128),256,0,stream>>>(AH,AL,WH1,WL1,WH2,WL2,nullptr,nullptr,FH,FL,rows,FFF,DD);
            k_cvt_w<<<dim3(DD / 64, FFF / 64), 256, 0, stream>>>(Wd, WDH, WDL, FFF, DD, 0, 0, wlo);
            k_bgemm<1,1,0><<<dim3(DD/128, rows/128),256,0,stream>>>(FH,FL,WDH,WDL,nullptr,nullptr,Hc,Hc,nullptr,nullptr,rows,DD,FFF);
        } else {
            for (int ffc = 0; ffc < FFF; ffc += 2048) {
                k_cvt_w<<<dim3(2048 / 64, DD / 64), 256, 0, stream>>>(Wg, cWgH, cWgL, DD, FFF, ffc, 0, wlo);
                k_cvt_w<<<dim3(2048 / 64, DD / 64), 256, 0, stream>>>(Wu, cWuH, cWuL, DD, FFF, ffc, 0, wlo);
                if (hiP) k_bgemm<3,0,1><<<dim3(16, rows/128),256,0,stream>>>(AH,AL,cWgH,cWgL,cWuH,cWuL,nullptr,nullptr,cFH,cFL,rows,2048,DD);
                else     k_bgemm<1,0,1><<<dim3(16, rows/128),256,0,stream>>>(AH,AL,cWgH,cWgL,cWuH,cWuL,nullptr,nullptr,cFH,cFL,rows,2048,DD);
                k_cvt_w<<<dim3(DD / 64, 2048 / 64), 256, 0, stream>>>(Wd + (size_t)ffc * DD, cWdH, cWdL, 2048, DD, 0, 0, wlo);
                if (hiP) k_bgemm<3,1,0><<<dim3(DD/128, rows/128),256,0,stream>>>(cFH,cFL,cWdH,cWdL,nullptr,nullptr,Hc,Hc,nullptr,nullptr,rows,DD,2048);
                else     k_bgemm<1,1,0><<<dim3(DD/128, rows/128),256,0,stream>>>(cFH,cFL,cWdH,cWdL,nullptr,nullptr,Hc,Hc,nullptr,nullptr,rows,DD,2048);
            }
        }
    }

    // ---- final rmsnorm + lm_head ----
    int rows = BBATCH * s;   // 1024
    u16* AHf = (u16*)Nc;
    u16* ALf = AHf + (size_t)rows * DD;
    u16* LmH = bigws ? (u16*)(ws + 6 * R) : (u16*)CQKV;
    k_rmsnorm_cvt<<<rows, 256, 0, stream>>>(Hc, lnf, AHf, ALf);
    k_cvt_w<<<dim3(VV / 64, DD / 64), 256, 0, stream>>>(lm_head, LmH, LmH, DD, VV, 0, 0, 0);
    if (bigws) {
        k_bg256<1,0,0><<<dim3(VV / 256, rows / 256), 512, 0, stream>>>(
            AHf, ALf, LmH, LmH, (float*)d_out, nullptr, nullptr, nullptr, nullptr,
            rows, VV, DD, DD);
    } else {
        k_bgemm<1,0,0><<<dim3(VV / 128, rows / 128), 256, 0, stream>>>(
            AHf, ALf, LmH, LmH, nullptr, nullptr, nullptr, (float*)d_out,
            nullptr, nullptr, rows, VV, DD);
    }
}

// Round 16
// 4528.726 us; speedup vs baseline: 1.0429x; 1.0429x over previous
//
#include <hip/hip_runtime.h>
#include <math.h>

// ---------------------------------------------------------------------------
// SDTP forward, round 16 = revert to round 14 (best measured: 4527 us).
// r15's BK=32 pipeline regressed (barrier cadence doubled, MFMA/sync halved,
// frag re-reads); reverting per post-mortem discipline.
// ---------------------------------------------------------------------------

#define DD 2048
#define HH 16
#define DHH 128
#define FFF 8192
#define BBATCH 2
#define SSEQ 2048
#define VV 32000
#define LLAYERS 4

typedef float4 f4;
typedef __attribute__((ext_vector_type(8))) short short8;
typedef __attribute__((ext_vector_type(4))) float f32x4;
typedef unsigned short u16;

__device__ inline u16 bf16rne(float x) {
    unsigned u = __float_as_uint(x);
    unsigned r = (u + 0x7FFFu + ((u >> 16) & 1u)) >> 16;
    return (u16)r;
}
__device__ inline float bf16tof(u16 h) {
    return __uint_as_float(((unsigned)h) << 16);
}

__device__ __forceinline__ void gload16(const u16* g, u16* l) {
    __builtin_amdgcn_global_load_lds(
        (const __attribute__((address_space(1))) unsigned int*)g,
        (__attribute__((address_space(3))) unsigned int*)l, 16, 0, 0);
}

#define BARRIER() do { asm volatile("" ::: "memory"); \
    __builtin_amdgcn_s_barrier(); asm volatile("" ::: "memory"); } while (0)

// bijective XCD-aware block swizzle (m204), COLUMN-major orig
__device__ __forceinline__ void xcd_swz(int& bx, int& by) {
    int gy = gridDim.y;
    int nwg = gridDim.x * gy;
    int orig = bx * gy + by;
    int q = nwg >> 3, r = nwg & 7;
    int xcd = orig & 7, loc = orig >> 3;
    int swz = (xcd < r ? xcd * (q + 1) : r * (q + 1) + (xcd - r) * q) + loc;
    bx = swz / gy;
    by = swz % gy;
}

// ---------------- embedding / copies ----------------
__global__ void k_embed(const int* __restrict__ ids, const float* __restrict__ emb,
                        float* __restrict__ out) {
    int row = blockIdx.x;
    int id  = ids[row];
    const f4* src = (const f4*)(emb + (size_t)id * DD);
    f4*       dst = (f4*)(out + (size_t)row * DD);
    for (int i = threadIdx.x; i < DD / 4; i += blockDim.x) dst[i] = src[i];
}

__global__ void k_copy_int(const int* __restrict__ src, int* __restrict__ dst, int n) {
    int i = blockIdx.x * blockDim.x + threadIdx.x;
    if (i < n) dst[i] = src[i];
}

// H[i] += sum_z P[z*len + i]
__global__ void k_addN(float* __restrict__ H, const float* __restrict__ P,
                       long len, int nparts) {
    long i = (long)blockIdx.x * 256 + threadIdx.x;
    if (i >= len / 4) return;
    f4 h = ((f4*)H)[i];
    for (int z = 0; z < nparts; z++) {
        f4 p = ((const f4*)(P + (size_t)z * len))[i];
        h.x += p.x; h.y += p.y; h.z += p.z; h.w += p.w;
    }
    ((f4*)H)[i] = h;
}

// ---------------- rmsnorm -> bf16 hi/lo planes ----------------
__global__ __launch_bounds__(256) void k_rmsnorm_cvt(const float* __restrict__ x,
                                                     const float* __restrict__ w,
                                                     u16* __restrict__ OH,
                                                     u16* __restrict__ OL) {
    int row = blockIdx.x;
    const float* xr = x + (size_t)row * DD;
    float ss = 0.f;
    for (int i = threadIdx.x; i < DD / 4; i += blockDim.x) {
        f4 v = ((const f4*)xr)[i];
        ss += v.x * v.x + v.y * v.y + v.z * v.z + v.w * v.w;
    }
    for (int o = 32; o > 0; o >>= 1) ss += __shfl_down(ss, o);
    __shared__ float red[4];
    int wid = threadIdx.x >> 6, lane = threadIdx.x & 63;
    if (lane == 0) red[wid] = ss;
    __syncthreads();
    float tot = red[0] + red[1] + red[2] + red[3];
    float inv = 1.0f / sqrtf(tot / (float)DD + 1e-6f);
    for (int i = threadIdx.x; i < DD / 4; i += blockDim.x) {
        f4 v = ((const f4*)xr)[i];
        f4 wv = ((const f4*)w)[i];
        float o[4];
        o[0] = v.x * wv.x * inv; o[1] = v.y * wv.y * inv;
        o[2] = v.z * wv.z * inv; o[3] = v.w * wv.w * inv;
        ushort4 hv, lv;
        u16* hp = (u16*)&hv; u16* lp = (u16*)&lv;
#pragma unroll
        for (int j = 0; j < 4; j++) {
            u16 h = bf16rne(o[j]);
            hp[j] = h;
            lp[j] = bf16rne(o[j] - bf16tof(h));
        }
        *(ushort4*)&OH[(size_t)row * DD + i * 4] = hv;
        *(ushort4*)&OL[(size_t)row * DD + i * 4] = lv;
    }
}

// ---------------- weight transpose+convert: W[K][N] -> planes [n][K] -------
__global__ __launch_bounds__(256) void k_cvt_w(const float* __restrict__ W,
                                               u16* __restrict__ WtH,
                                               u16* __restrict__ WtL,
                                               int K, int N, int nc0, int dn0,
                                               int writeLo) {
    __shared__ float T[64][65];
    int tid = threadIdx.x;
    int n0g = nc0 + blockIdx.x * 64;
    int k0  = blockIdx.y * 64;
#pragma unroll
    for (int it = 0; it < 4; it++) {
        int r = it * 16 + (tid >> 4);
        int c4 = (tid & 15) * 4;
        f4 v = *(const f4*)(W + (size_t)(k0 + r) * N + n0g + c4);
        T[r][c4 + 0] = v.x; T[r][c4 + 1] = v.y;
        T[r][c4 + 2] = v.z; T[r][c4 + 3] = v.w;
    }
    __syncthreads();
    int nl = tid >> 2;
    int ks = (tid & 3) * 16;
    u16 hi[16], lo[16];
#pragma unroll
    for (int j = 0; j < 16; j++) {
        float v = T[ks + j][nl];
        u16 h = bf16rne(v);
        hi[j] = h;
        lo[j] = bf16rne(v - bf16tof(h));
    }
    size_t base = (size_t)(dn0 + blockIdx.x * 64 + nl) * K + k0 + ks;
    *(short8*)&WtH[base]     = *(short8*)&hi[0];
    *(short8*)&WtH[base + 8] = *(short8*)&hi[8];
    if (writeLo) {
        *(short8*)&WtL[base]     = *(short8*)&lo[0];
        *(short8*)&WtL[base + 8] = *(short8*)&lo[8];
    }
}

// ---------------- bf16 MFMA GEMM, m97 structure (128x128) ----------------
template <int PASSES, int RES, int DUAL>
__global__ __launch_bounds__(256, 2) void k_bgemm(const u16* __restrict__ AH,
                                                  const u16* __restrict__ AL,
                                                  const u16* __restrict__ B1H,
                                                  const u16* __restrict__ B1L,
                                                  const u16* __restrict__ B2H,
                                                  const u16* __restrict__ B2L,
                                                  const float* __restrict__ Rsrc,
                                                  float* __restrict__ C,
                                                  u16* __restrict__ OH,
                                                  u16* __restrict__ OL,
                                                  int M, int ldC, int K) {
    constexpr int NW = DUAL ? 2 : 1;
    __shared__ u16 As[128 * 32];
    __shared__ u16 Bs[NW][128 * 32];
    int tid = threadIdx.x;
    int bx = blockIdx.x, by = blockIdx.y;
    xcd_swz(bx, by);
    int m0 = by * 128, n0 = bx * 128;
    int lane = tid & 63, w = tid >> 6;
    int wm = w >> 1, wn = w & 1;
    int lr = lane & 15, lq = lane >> 4;
    int grow = lane >> 2;
    int gcol = (lane & 3) * 8;

    f32x4 acc[NW][4][4];
#pragma unroll
    for (int u = 0; u < NW; u++)
#pragma unroll
        for (int i = 0; i < 4; i++)
#pragma unroll
            for (int j = 0; j < 4; j++)
#pragma unroll
                for (int r = 0; r < 4; r++) acc[u][i][j][r] = 0.f;

    const int KT = PASSES * K;
    for (int kb = 0; kb < KT; kb += 32) {
        int p  = (PASSES > 1) ? ((kb >= 2 * K) ? 2 : ((kb >= K) ? 1 : 0)) : 0;
        int ks = kb - p * K;
        const u16* Ab = ((p == 2) ? AL  : AH)  + (size_t)(m0 + w * 32) * K + ks;
        const u16* Bb = ((p == 1) ? B1L : B1H) + (size_t)(n0 + w * 32) * K + ks;
        __syncthreads();
        gload16(Ab + (size_t)grow * K + gcol,        &As[w * 1024]);
        gload16(Ab + (size_t)(grow + 16) * K + gcol, &As[w * 1024 + 512]);
        gload16(Bb + (size_t)grow * K + gcol,        &Bs[0][w * 1024]);
        gload16(Bb + (size_t)(grow + 16) * K + gcol, &Bs[0][w * 1024 + 512]);
        if constexpr (DUAL) {
            const u16* B2b = ((p == 1) ? B2L : B2H) + (size_t)(n0 + w * 32) * K + ks;
            gload16(B2b + (size_t)grow * K + gcol,        &Bs[1][w * 1024]);
            gload16(B2b + (size_t)(grow + 16) * K + gcol, &Bs[1][w * 1024 + 512]);
        }
        __syncthreads();
        short8 a[4];
#pragma unroll
        for (int i = 0; i < 4; i++)
            a[i] = *(const short8*)&As[(wm * 64 + i * 16 + lr) * 32 + lq * 8];
#pragma unroll
        for (int u = 0; u < NW; u++) {
#pragma unroll
            for (int j = 0; j < 4; j++) {
                short8 b = *(const short8*)&Bs[u][(wn * 64 + j * 16 + lr) * 32 + lq * 8];
#pragma unroll
                for (int i = 0; i < 4; i++)
                    acc[u][i][j] = __builtin_amdgcn_mfma_f32_16x16x32_bf16(
                        a[i], b, acc[u][i][j], 0, 0, 0);
            }
        }
    }
#pragma unroll
    for (int i = 0; i < 4; i++) {
#pragma unroll
        for (int j = 0; j < 4; j++) {
            int gm = m0 + wm * 64 + i * 16 + lq * 4;
            int gn = n0 + wn * 64 + j * 16 + lr;
#pragma unroll
            for (int r = 0; r < 4; r++) {
                size_t off = (size_t)(gm + r) * ldC + gn;
                if constexpr (DUAL) {
                    float g = acc[0][i][j][r], uu = acc[1][i][j][r];
                    float v = g / (1.0f + expf(-g)) * uu;
                    u16 h = bf16rne(v);
                    OH[off] = h;
                    OL[off] = bf16rne(v - bf16tof(h));
                } else {
                    float v = acc[0][i][j][r];
                    if constexpr (RES) v += Rsrc[off];
                    C[off] = v;
                }
            }
        }
    }
}

// ---------------- 256x256-tile GEMM, batch-issue tile schedule ----------------
// EPI: epilogue reads gate planes GEH/GEL at off, v = silu(g) * acc (fp32 u).
template <int PASSES, int PLANE, int EPI>
__global__ __launch_bounds__(512, 2) void k_bg256(const u16* __restrict__ AH,
                                                  const u16* __restrict__ AL,
                                                  const u16* __restrict__ BH,
                                                  const u16* __restrict__ BL,
                                                  float* __restrict__ C,
                                                  u16* __restrict__ OH,
                                                  u16* __restrict__ OL,
                                                  const u16* __restrict__ GEH,
                                                  const u16* __restrict__ GEL,
                                                  int M, int ldC, int K, int ld) {
    __shared__ u16 SM[65536];   // 128 KB: 2 bufs x 64KB
    int tid = threadIdx.x;
    int bx = blockIdx.x, by = blockIdx.y;
    xcd_swz(bx, by);
    {   // split-K part select
        size_t zo = (size_t)blockIdx.z * K;
        AH += zo; BH += zo;
        if constexpr (PASSES > 1) { AL += zo; BL += zo; }
        if constexpr (!PLANE) C += (size_t)blockIdx.z * ((size_t)M * ldC);
    }
    int m0 = by * 256, n0 = bx * 256;
    int w = tid >> 6, lane = tid & 63;
    int wm = w >> 2, wn = w & 3;
    int lr = lane & 15, lq = lane >> 4;

    f32x4 acc[8][4];
#pragma unroll
    for (int i = 0; i < 8; i++)
#pragma unroll
        for (int j = 0; j < 4; j++)
#pragma unroll
            for (int r = 0; r < 4; r++) acc[i][j][r] = 0.f;

    auto ASRC = [&](int T) -> const u16* {
        int kb = T * 64;
        if (PASSES > 1) {
            if (kb >= 2 * K) return AL + (kb - 2 * K);
            if (kb >= K)     return AH + (kb - K);
        }
        return AH + kb;
    };
    auto BSRC = [&](int T) -> const u16* {
        int kb = T * 64;
        if (PASSES > 1) {
            if (kb >= 2 * K) return BH + (kb - 2 * K);
            if (kb >= K)     return BL + (kb - K);
        }
        return BH + kb;
    };
    int srr = lane >> 3;
    int scc = ((lane & 7) ^ srr) * 8;   // pre-swizzled source column
    auto STAGE_A = [&](int T, int h, int buf) {
        const u16* s = ASRC(T) + (size_t)(m0 + h * 128 + w * 16 + srr) * ld + scc;
        u16* d = SM + buf * 32768 + h * 8192 + w * 16 * 64;
        gload16(s, d);
        gload16(s + (size_t)8 * ld, d + 8 * 64);
    };
    auto STAGE_B = [&](int T, int h, int buf) {
        const u16* s = BSRC(T) + (size_t)(n0 + h * 128 + w * 16 + srr) * ld + scc;
        u16* d = SM + buf * 32768 + 16384 + h * 8192 + w * 16 * 64;
        gload16(s, d);
        gload16(s + (size_t)8 * ld, d + 8 * 64);
    };
    auto RD_A = [&](const u16* SMb, int MH, short8 (&aF)[4][2]) {
        const u16* Ab = SMb + MH * 8192;
#pragma unroll
        for (int i = 0; i < 4; i++)
#pragma unroll
            for (int kk = 0; kk < 2; kk++)
                aF[i][kk] = *(const short8*)&Ab[(wm * 64 + i * 16 + lr) * 64 +
                                                (((kk * 4 + lq) ^ (lr & 7)) * 8)];
    };
    auto RD_B = [&](const u16* SMb, int NH, short8 (&bF)[2][2]) {
        const u16* Bb = SMb + 16384 + NH * 8192;
#pragma unroll
        for (int j = 0; j < 2; j++)
#pragma unroll
            for (int kk = 0; kk < 2; kk++)
                bF[j][kk] = *(const short8*)&Bb[(wn * 32 + j * 16 + lr) * 64 +
                                                (((kk * 4 + lq) ^ (lr & 7)) * 8)];
    };

    const int NT = (PASSES * K) >> 6;
    STAGE_A(0, 0, 0); STAGE_B(0, 0, 0);
    STAGE_A(0, 1, 0); STAGE_B(0, 1, 0);
    asm volatile("s_waitcnt vmcnt(0)" ::: "memory");
    BARRIER();

    for (int T = 0; T < NT; T++) {
        int cur = T & 1;
        const u16* SMb = SM + cur * 32768;
        short8 a0[4][2], a1[4][2], b0[2][2], b1[2][2];
        if (T + 1 < NT) { STAGE_A(T + 1, 0, cur ^ 1); STAGE_B(T + 1, 0, cur ^ 1); }
        RD_A(SMb, 0, a0);
        RD_B(SMb, 0, b0);
        if (T + 1 < NT) { STAGE_A(T + 1, 1, cur ^ 1); STAGE_B(T + 1, 1, cur ^ 1); }
        RD_B(SMb, 1, b1);
        RD_A(SMb, 1, a1);
        __builtin_amdgcn_s_setprio(1);
#pragma unroll
        for (int kk = 0; kk < 2; kk++)
#pragma unroll
            for (int j = 0; j < 2; j++)
#pragma unroll
                for (int i = 0; i < 4; i++)
                    acc[i][j] = __builtin_amdgcn_mfma_f32_16x16x32_bf16(
                        a0[i][kk], b0[j][kk], acc[i][j], 0, 0, 0);
#pragma unroll
        for (int kk = 0; kk < 2; kk++)
#pragma unroll
            for (int j = 0; j < 2; j++)
#pragma unroll
                for (int i = 0; i < 4; i++)
                    acc[i][2 + j] = __builtin_amdgcn_mfma_f32_16x16x32_bf16(
                        a0[i][kk], b1[j][kk], acc[i][2 + j], 0, 0, 0);
#pragma unroll
        for (int kk = 0; kk < 2; kk++)
#pragma unroll
            for (int j = 0; j < 2; j++)
#pragma unroll
                for (int i = 0; i < 4; i++)
                    acc[4 + i][j] = __builtin_amdgcn_mfma_f32_16x16x32_bf16(
                        a1[i][kk], b0[j][kk], acc[4 + i][j], 0, 0, 0);
#pragma unroll
        for (int kk = 0; kk < 2; kk++)
#pragma unroll
            for (int j = 0; j < 2; j++)
#pragma unroll
                for (int i = 0; i < 4; i++)
                    acc[4 + i][2 + j] = __builtin_amdgcn_mfma_f32_16x16x32_bf16(
                        a1[i][kk], b1[j][kk], acc[4 + i][2 + j], 0, 0, 0);
        __builtin_amdgcn_s_setprio(0);
        if (T + 1 < NT) {
            asm volatile("s_waitcnt vmcnt(0)" ::: "memory");
            BARRIER();
        }
    }

#pragma unroll
    for (int i16 = 0; i16 < 8; i16++) {
#pragma unroll
        for (int jj = 0; jj < 4; jj++) {
            int gm = m0 + (i16 >> 2) * 128 + wm * 64 + (i16 & 3) * 16 + lq * 4;
            int gn = n0 + (jj >> 1) * 128 + wn * 32 + (jj & 1) * 16 + lr;
#pragma unroll
            for (int r = 0; r < 4; r++) {
                size_t off = (size_t)(gm + r) * ldC + gn;
                float v = acc[i16][jj][r];
                if constexpr (PLANE) {
                    if constexpr (EPI) {
                        float g = bf16tof(GEH[off]) + bf16tof(GEL[off]);
                        v = g / (1.0f + expf(-g)) * v;
                    }
                    u16 h = bf16rne(v);
                    OH[off] = h;
                    OL[off] = bf16rne(v - bf16tof(h));
                } else {
                    C[off] = v;
                }
            }
        }
    }
}

// ---------------- RoPE ----------------
__global__ void k_rope_table(float* __restrict__ cosT, float* __restrict__ sinT) {
    int idx = blockIdx.x * blockDim.x + threadIdx.x;
    if (idx >= SSEQ * 64) return;
    int pos = idx >> 6, d = idx & 63;
    float p   = (float)pow(10000.0, (double)d * (1.0 / 64.0));
    float inv = 1.0f / p;
    float ang = (float)pos * inv;
    cosT[idx] = (float)cos((double)ang);
    sinT[idx] = (float)sin((double)ang);
}

// tier-D only: in-place rotate Q,K of CQKV
__global__ void k_rope(float* __restrict__ C,
                       const float* __restrict__ cosT, const float* __restrict__ sinT,
                       int s, int ld) {
    int bi = blockIdx.x;
    int h = bi % HH;
    int i = (bi / HH) % s;
    size_t base = (size_t)(bi / HH) * ld + h * DHH;
    int d = threadIdx.x;
    float c  = cosT[i * 64 + d];
    float sn = sinT[i * 64 + d];
    float x1 = C[base + d], x2 = C[base + 64 + d];
    C[base + d]      = x1 * c - x2 * sn;
    C[base + 64 + d] = x1 * sn + x2 * c;
    x1 = C[base + 2048 + d]; x2 = C[base + 2048 + 64 + d];
    C[base + 2048 + d]      = x1 * c - x2 * sn;
    C[base + 2048 + 64 + d] = x1 * sn + x2 * c;
}

// ---------------- fused RoPE + Q/K fp32 -> bf16 hi/lo planes ----------------
// Bit-identical to k_rope followed by the old k_cvt_qk (same fp32 expressions).
__global__ __launch_bounds__(256) void k_cvt_qkr(const float* __restrict__ C,
                                                 const float* __restrict__ cosT,
                                                 const float* __restrict__ sinT,
                                                 u16* __restrict__ QHp, u16* __restrict__ QLp,
                                                 u16* __restrict__ KHp, u16* __restrict__ KLp,
                                                 int s) {
    int row = blockIdx.x;
    int i = row % s;
    int c = threadIdx.x * 8;      // col within 2048, 8-aligned (inside one 64-half)
    int d = c & 127;
    int hi2 = (d >= 64) ? 1 : 0;
    int dd = d - hi2 * 64;        // 0..56, table base
    const float* tb = cosT + (size_t)i * 64;
    const float* ts = sinT + (size_t)i * 64;
#pragma unroll
    for (int sec = 0; sec < 2; sec++) {
        const float* src = C + (size_t)row * 6144 + sec * 2048;
        int base1 = c - hi2 * 64;
        float o[8];
#pragma unroll
        for (int q = 0; q < 2; q++) {
            f4 v1 = *(const f4*)(src + base1 + q * 4);
            f4 v2 = *(const f4*)(src + base1 + 64 + q * 4);
            float a1[4] = {v1.x, v1.y, v1.z, v1.w};
            float a2[4] = {v2.x, v2.y, v2.z, v2.w};
#pragma unroll
            for (int e = 0; e < 4; e++) {
                float cc = tb[dd + q * 4 + e];
                float sn = ts[dd + q * 4 + e];
                o[q * 4 + e] = hi2 ? (a1[e] * sn + a2[e] * cc)
                                   : (a1[e] * cc - a2[e] * sn);
            }
        }
        u16 hbuf[8], lbuf[8];
#pragma unroll
        for (int e = 0; e < 8; e++) {
            u16 h = bf16rne(o[e]);
            hbuf[e] = h;
            lbuf[e] = bf16rne(o[e] - bf16tof(h));
        }
        u16* dh = (sec ? KHp : QHp) + (size_t)row * 2048 + c;
        u16* dl = (sec ? KLp : QLp) + (size_t)row * 2048 + c;
        *(short8*)dh = *(short8*)&hbuf[0];
        *(short8*)dl = *(short8*)&lbuf[0];
    }
}

// ---------------- V -> transposed swizzled planes Vt[b*h][128][s] ----------
__global__ __launch_bounds__(256) void k_cvt_vt(const float* __restrict__ C,
                                                u16* __restrict__ VtH,
                                                u16* __restrict__ VtL, int s) {
    __shared__ float T[64][132];
    int bh = blockIdx.y;
    int h = bh & 15, b = bh >> 4;
    int kv0 = blockIdx.x * 64;
    int t = threadIdx.x;
#pragma unroll
    for (int it = 0; it < 8; it++) {
        int kv = it * 8 + (t >> 5);
        int c4 = (t & 31) * 4;
        f4 v = *(const f4*)(C + (size_t)((size_t)b * s + kv0 + kv) * 6144 + 4096 + h * 128 + c4);
        T[kv][c4 + 0] = v.x; T[kv][c4 + 1] = v.y;
        T[kv][c4 + 2] = v.z; T[kv][c4 + 3] = v.w;
    }
    __syncthreads();
    int d = t >> 1, seg = t & 1;
    size_t base = ((size_t)bh * 128 + d) * s + kv0 + seg * 32;
#pragma unroll
    for (int g = 0; g < 4; g++) {
        u16 h8[8], l8[8];
#pragma unroll
        for (int e = 0; e < 8; e++) {
            float v = T[seg * 32 + g * 8 + e][d];
            u16 hh = bf16rne(v);
            h8[e] = hh;
            l8[e] = bf16rne(v - bf16tof(hh));
        }
        int gp = (g ^ ((d >> 1) & 3)) * 8;
        *(short8*)&VtH[base + gp] = *(short8*)&h8[0];
        *(short8*)&VtL[base + gp] = *(short8*)&l8[0];
    }
}

// ---------------- MFMA flash attention (QBLK=128, pipelined, bh-chunked) ----
template <int PASSES>
__global__ __launch_bounds__(256, 2) void k_attn_mfma(
        const u16* __restrict__ QHp, const u16* __restrict__ QLp,
        const u16* __restrict__ KHp, const u16* __restrict__ KLp,
        const u16* __restrict__ VtH, const u16* __restrict__ VtL,
        const int* __restrict__ mask,
        u16* __restrict__ OH, u16* __restrict__ OL, int s) {
    constexpr int BUFU = (PASSES > 1) ? 16384 : 8192;
    constexpr int VOFF = (PASSES > 1) ? 8192 : 4096;
    __shared__ u16 SM[2 * BUFU + 5120];
    int tid = threadIdx.x, lane = tid & 63, w = tid >> 6;
    int lr = lane & 15, lq = lane >> 4;
    int grow = lane >> 2;
    int sgcol = (((lane & 3) ^ ((lane >> 3) & 3))) * 8;
    int gcol  = (lane & 3) * 8;
    int rc = (lq ^ ((lr >> 1) & 3)) * 8;
    int gx = gridDim.x;
    int NB = gx * gridDim.y;
    int orig = blockIdx.y * gx + blockIdx.x;
    int qq = NB >> 3, rr = NB & 7;
    int xcd = orig & 7, loc = orig >> 3;
    int swz = (xcd < rr ? xcd * (qq + 1) : rr * (qq + 1) + (xcd - rr) * qq) + loc;
    int bh = swz / gx;
    int qt = gx - 1 - (swz % gx);
    int h = bh & 15, b = bh >> 4;
    int q0 = qt * 128;
    size_t rb = (size_t)b * s;
    const u16* vtH = VtH + (size_t)bh * 128 * s;
    const u16* vtL = VtL + (size_t)bh * 128 * s;
    u16* PHw = SM + 2 * BUFU + w * 1280;
    u16* PLw = PHw + 640;
    const float scale = 0.08838834764831845f;

    short8 qh[2][4], ql[2][4];
#pragma unroll
    for (int st = 0; st < 2; st++) {
        const u16* qp = QHp + (rb + q0 + st * 64) * 2048 + h * 128 + w * 32;
#pragma unroll
        for (int it = 0; it < 4; it++)
            gload16(qp + (size_t)(it * 16 + grow) * 2048 + sgcol, SM + w * 2048 + it * 512);
        __syncthreads();
#pragma unroll
        for (int ks = 0; ks < 4; ks++)
            qh[st][ks] = *(const short8*)&SM[ks * 2048 + (w * 16 + lr) * 32 + rc];
        if constexpr (PASSES > 1) {
            __syncthreads();
            const u16* qp2 = QLp + (rb + q0 + st * 64) * 2048 + h * 128 + w * 32;
#pragma unroll
            for (int it = 0; it < 4; it++)
                gload16(qp2 + (size_t)(it * 16 + grow) * 2048 + sgcol, SM + w * 2048 + it * 512);
            __syncthreads();
#pragma unroll
            for (int ks = 0; ks < 4; ks++)
                ql[st][ks] = *(const short8*)&SM[ks * 2048 + (w * 16 + lr) * 32 + rc];
        }
        __syncthreads();
    }

    auto kv_stage = [&](int t, int buf) {
        u16* base = SM + buf * BUFU;
        const u16* kp = KHp + (rb + t * 32) * 2048 + h * 128 + w * 32;
        gload16(kp + (size_t)grow * 2048 + sgcol,        base + w * 1024);
        gload16(kp + (size_t)(16 + grow) * 2048 + sgcol, base + w * 1024 + 512);
        const u16* vp = vtH + (size_t)(w * 32) * s + t * 32;
        gload16(vp + (size_t)grow * s + gcol,        base + VOFF + (w * 32) * 32);
        gload16(vp + (size_t)(16 + grow) * s + gcol, base + VOFF + (w * 32 + 16) * 32);
        if constexpr (PASSES > 1) {
            const u16* kp2 = KLp + (rb + t * 32) * 2048 + h * 128 + w * 32;
            gload16(kp2 + (size_t)grow * 2048 + sgcol,        base + 4096 + w * 1024);
            gload16(kp2 + (size_t)(16 + grow) * 2048 + sgcol, base + 4096 + w * 1024 + 512);
            const u16* vp2 = vtL + (size_t)(w * 32) * s + t * 32;
            gload16(vp2 + (size_t)grow * s + gcol,        base + 12288 + (w * 32) * 32);
            gload16(vp2 + (size_t)(16 + grow) * s + gcol, base + 12288 + (w * 32 + 16) * 32);
        }
    };

    f32x4 o_acc[2][8];
#pragma unroll
    for (int st = 0; st < 2; st++)
#pragma unroll
        for (int j = 0; j < 8; j++)
#pragma unroll
            for (int r = 0; r < 4; r++) o_acc[st][j][r] = 0.f;
    float m_run[2][4], l_run[2][4];
#pragma unroll
    for (int st = 0; st < 2; st++)
#pragma unroll
        for (int r = 0; r < 4; r++) { m_run[st][r] = -3.0e38f; l_run[st][r] = 0.f; }

    int nt = (q0 + 128) >> 5;
    int mv0 = mask[rb + lr];
    int mv1 = mask[rb + 16 + lr];
    kv_stage(0, 0);
    for (int t = 0; t < nt; t++) {
        int bsel = t & 1;
        if (t + 1 < nt) {
            kv_stage(t + 1, 1 - bsel);
            if constexpr (PASSES > 1)
                asm volatile("s_waitcnt vmcnt(8)" ::: "memory");
            else
                asm volatile("s_waitcnt vmcnt(4)" ::: "memory");
        } else {
            asm volatile("s_waitcnt vmcnt(0)" ::: "memory");
        }
        BARRIER();
        int nmv0 = mv0, nmv1 = mv1;
        if (t + 1 < nt) {
            nmv0 = mask[rb + (t + 1) * 32 + lr];
            nmv1 = mask[rb + (t + 1) * 32 + 16 + lr];
        }
        const u16* KsH = SM + bsel * BUFU;
        const u16* KsL = KsH + 4096;
        const u16* VsH = SM + bsel * BUFU + VOFF;
        const u16* VsL = SM + bsel * BUFU + 12288;
#pragma unroll
        for (int st = 0; st < 2; st++) {
            if (t * 32 > q0 + st * 64 + w * 16 + 15) continue;
            f32x4 sa[2];
#pragma unroll
            for (int j = 0; j < 2; j++)
#pragma unroll
                for (int r = 0; r < 4; r++) sa[j][r] = 0.f;
#pragma unroll
            for (int j = 0; j < 2; j++) {
#pragma unroll
                for (int ks = 0; ks < 4; ks++) {
                    short8 kb = *(const short8*)&KsH[ks * 1024 + (j * 16 + lr) * 32 + rc];
                    sa[j] = __builtin_amdgcn_mfma_f32_16x16x32_bf16(qh[st][ks], kb, sa[j], 0, 0, 0);
                    if constexpr (PASSES > 1) {
                        short8 kl2 = *(const short8*)&KsL[ks * 1024 + (j * 16 + lr) * 32 + rc];
                        sa[j] = __builtin_amdgcn_mfma_f32_16x16x32_bf16(qh[st][ks], kl2, sa[j], 0, 0, 0);
                        sa[j] = __builtin_amdgcn_mfma_f32_16x16x32_bf16(ql[st][ks], kb, sa[j], 0, 0, 0);
                    }
                }
            }
            float sclv[4];
#pragma unroll
            for (int r = 0; r < 4; r++) {
                int ig = q0 + st * 64 + w * 16 + lq * 4 + r;
                float v0 = (t * 32 + lr <= ig && mv0 > 0) ? sa[0][r] * scale : -1.0e9f;
                float v1 = (t * 32 + 16 + lr <= ig && mv1 > 0) ? sa[1][r] * scale : -1.0e9f;
                float mx = fmaxf(v0, v1);
                mx = fmaxf(mx, __shfl_xor(mx, 1));
                mx = fmaxf(mx, __shfl_xor(mx, 2));
                mx = fmaxf(mx, __shfl_xor(mx, 4));
                mx = fmaxf(mx, __shfl_xor(mx, 8));
                float mo = m_run[st][r];
                float mn = fmaxf(mo, mx);
                float p0 = expf(v0 - mn), p1 = expf(v1 - mn);
                float ps = p0 + p1;
                ps += __shfl_xor(ps, 1);
                ps += __shfl_xor(ps, 2);
                ps += __shfl_xor(ps, 4);
                ps += __shfl_xor(ps, 8);
                sclv[r] = expf(mo - mn);
                m_run[st][r] = mn;
                l_run[st][r] = l_run[st][r] * sclv[r] + ps;
                int prow = lq * 4 + r;
                u16 h0 = bf16rne(p0);
                u16 h1 = bf16rne(p1);
                PHw[prow * 40 + lr] = h0;
                PHw[prow * 40 + 16 + lr] = h1;
                if constexpr (PASSES > 1) {
                    PLw[prow * 40 + lr] = bf16rne(p0 - bf16tof(h0));
                    PLw[prow * 40 + 16 + lr] = bf16rne(p1 - bf16tof(h1));
                }
            }
#pragma unroll
            for (int j = 0; j < 8; j++)
#pragma unroll
                for (int r = 0; r < 4; r++) o_acc[st][j][r] *= sclv[r];
            short8 ph = *(const short8*)&PHw[lr * 40 + lq * 8];
            short8 pl;
            if constexpr (PASSES > 1) pl = *(const short8*)&PLw[lr * 40 + lq * 8];
#pragma unroll
            for (int j = 0; j < 8; j++) {
                int vrow = j * 16 + lr;
                short8 vh = *(const short8*)&VsH[vrow * 32 + rc];
                o_acc[st][j] = __builtin_amdgcn_mfma_f32_16x16x32_bf16(ph, vh, o_acc[st][j], 0, 0, 0);
                if constexpr (PASSES > 1) {
                    short8 vl = *(const short8*)&VsL[vrow * 32 + rc];
                    o_acc[st][j] = __builtin_amdgcn_mfma_f32_16x16x32_bf16(ph, vl, o_acc[st][j], 0, 0, 0);
                    o_acc[st][j] = __builtin_amdgcn_mfma_f32_16x16x32_bf16(pl, vh, o_acc[st][j], 0, 0, 0);
                }
            }
        }
        BARRIER();
        mv0 = nmv0; mv1 = nmv1;
    }
#pragma unroll
    for (int st = 0; st < 2; st++) {
#pragma unroll
        for (int r = 0; r < 4; r++) {
            float linv = 1.0f / l_run[st][r];
            size_t rowoff = (rb + q0 + st * 64 + w * 16 + lq * 4 + r) * 2048 + h * 128 + lr;
#pragma unroll
            for (int j = 0; j < 8; j++) {
                float v = o_acc[st][j][r] * linv;
                u16 hh = bf16rne(v);
                OH[rowoff + j * 16] = hh;
                OL[rowoff + j * 16] = bf16rne(v - bf16tof(hh));
            }
        }
    }
}

// ---------------- fp32 flash attention (tier D fallback) ----------------
__global__ __launch_bounds__(256, 2) void k_attn_f32(const float* __restrict__ Q,
                                                     const float* __restrict__ K,
                                                     const float* __restrict__ V,
                                                     const int* __restrict__ mask,
                                                     u16* __restrict__ OH,
                                                     u16* __restrict__ OL, int s, int ld) {
    int qt = blockIdx.x, bh = blockIdx.y;
    int h = bh & (HH - 1), b = bh >> 4;
    __shared__ float Qs[64][132];
    __shared__ float Ks[32 * 128];
    __shared__ float Vs[32][132];
    __shared__ float Ps[64][36];
    __shared__ float mrow[64], lrow[64];
    int tid = threadIdx.x;
    int tx = tid & 15, ty = tid >> 4;

#pragma unroll
    for (int p = 0; p < 2; p++) {
        int r = p * 32 + (tid >> 3);
        int kb = (tid & 7) * 4;
        const float* src = Q + (size_t)(b * s + qt * 64 + r) * ld + h * DHH;
#pragma unroll
        for (int q = 0; q < 4; q++)
            *(f4*)&Qs[r][kb + 32 * q] = *(const f4*)(src + kb + 32 * q);
    }
    if (tid < 64) { mrow[tid] = -3.0e38f; lrow[tid] = 0.f; }

    float acc[4][8];
#pragma unroll
    for (int i = 0; i < 4; i++)
#pragma unroll
        for (int c = 0; c < 8; c++) acc[i][c] = 0.f;
    const float scale = 0.08838834764831845f;

    int ktmax = 2 * (qt + 1);
    for (int kt = 0; kt < ktmax; kt++) {
        __syncthreads();
#pragma unroll
        for (int p = 0; p < 4; p++) {
            int c = p * 8 + (tid >> 5);
            int kk = (tid & 31) * 4;
            size_t g = (size_t)(b * s + kt * 32 + c) * ld + h * DHH + kk;
            f4 kv = *(const f4*)(K + g);
            int ch = (kk >> 2) ^ (c >> 1);
            *(f4*)&Ks[c * 128 + ch * 4] = kv;
            *(f4*)&Vs[c][kk] = *(const f4*)(V + g);
        }
        __syncthreads();
        float sv[4][2];
#pragma unroll
        for (int i = 0; i < 4; i++) { sv[i][0] = 0.f; sv[i][1] = 0.f; }
        for (int kk = 0; kk < 128; kk += 4) {
            f4 qv[4];
#pragma unroll
            for (int i = 0; i < 4; i++) qv[i] = *(const f4*)&Qs[ty * 4 + i][kk];
#pragma unroll
            for (int j = 0; j < 2; j++) {
                int c = tx * 2 + j;
                int ch = (kk >> 2) ^ (c >> 1);
                f4 kv = *(const f4*)&Ks[c * 128 + ch * 4];
#pragma unroll
                for (int i = 0; i < 4; i++)
                    sv[i][j] += qv[i].x * kv.x + qv[i].y * kv.y +
                                qv[i].z * kv.z + qv[i].w * kv.w;
            }
        }
        float scl[4];
#pragma unroll
        for (int i = 0; i < 4; i++) {
            int r = ty * 4 + i;
            int igl = qt * 64 + r;
#pragma unroll
            for (int j = 0; j < 2; j++) {
                int jg = kt * 32 + tx * 2 + j;
                bool ok = (jg <= igl) && (mask[b * s + jg] > 0);
                sv[i][j] = ok ? sv[i][j] * scale : -1.0e9f;
            }
            float rmax = fmaxf(sv[i][0], sv[i][1]);
            rmax = fmaxf(rmax, __shfl_xor(rmax, 1));
            rmax = fmaxf(rmax, __shfl_xor(rmax, 2));
            rmax = fmaxf(rmax, __shfl_xor(rmax, 4));
            rmax = fmaxf(rmax, __shfl_xor(rmax, 8));
            float mold = mrow[r];
            float mnew = fmaxf(mold, rmax);
            float p0 = expf(sv[i][0] - mnew);
            float p1 = expf(sv[i][1] - mnew);
            float ps = p0 + p1;
            ps += __shfl_xor(ps, 1);
            ps += __shfl_xor(ps, 2);
            ps += __shfl_xor(ps, 4);
            ps += __shfl_xor(ps, 8);
            scl[i] = expf(mold - mnew);
            if (tx == 0) { mrow[r] = mnew; lrow[r] = lrow[r] * scl[i] + ps; }
            float2 pw; pw.x = p0; pw.y = p1;
            *(float2*)&Ps[r][tx * 2] = pw;
        }
        __syncthreads();
#pragma unroll
        for (int i = 0; i < 4; i++) {
            float sc = scl[i];
#pragma unroll
            for (int c = 0; c < 8; c++) acc[i][c] *= sc;
        }
        for (int jj = 0; jj < 32; jj += 4) {
            f4 pv[4];
#pragma unroll
            for (int i = 0; i < 4; i++) pv[i] = *(const f4*)&Ps[ty * 4 + i][jj];
#pragma unroll
            for (int j2 = 0; j2 < 4; j2++) {
                f4 va = *(const f4*)&Vs[jj + j2][tx * 4];
                f4 vb = *(const f4*)&Vs[jj + j2][64 + tx * 4];
#pragma unroll
                for (int i = 0; i < 4; i++) {
                    float p = (&pv[i].x)[j2];
                    acc[i][0] += p * va.x; acc[i][1] += p * va.y;
                    acc[i][2] += p * va.z; acc[i][3] += p * va.w;
                    acc[i][4] += p * vb.x; acc[i][5] += p * vb.y;
                    acc[i][6] += p * vb.z; acc[i][7] += p * vb.w;
                }
            }
        }
    }
    __syncthreads();
#pragma unroll
    for (int i = 0; i < 4; i++) {
        int r = ty * 4 + i;
        float linv = 1.0f / lrow[r];
        size_t ob = (size_t)(b * s + qt * 64 + r) * DD + h * DHH;
        ushort4 h1, l1, h2, l2;
        u16 *h1p = (u16*)&h1, *l1p = (u16*)&l1, *h2p = (u16*)&h2, *l2p = (u16*)&l2;
#pragma unroll
        for (int c = 0; c < 4; c++) {
            float v = acc[i][c] * linv;
            u16 hh = bf16rne(v);
            h1p[c] = hh; l1p[c] = bf16rne(v - bf16tof(hh));
            float v2 = acc[i][c + 4] * linv;
            u16 hh2 = bf16rne(v2);
            h2p[c] = hh2; l2p[c] = bf16rne(v2 - bf16tof(hh2));
        }
        *(ushort4*)&OH[ob + tx * 4] = h1;
        *(ushort4*)&OL[ob + tx * 4] = l1;
        *(ushort4*)&OH[ob + 64 + tx * 4] = h2;
        *(ushort4*)&OL[ob + 64 + tx * 4] = l2;
    }
}

// ---------------- prune scoring / selection ----------------
__global__ __launch_bounds__(256) void k_score(const float* __restrict__ Hb,
                                               const float* __restrict__ srow,
                                               float* __restrict__ sc) {
    int row = blockIdx.x;
    const float* xr = Hb + (size_t)row * DD;
    float ss = 0.f;
    for (int i = threadIdx.x; i < DD / 4; i += blockDim.x) {
        f4 a = ((const f4*)xr)[i];
        f4 w = ((const f4*)srow)[i];
        ss += a.x * w.x + a.y * w.y + a.z * w.z + a.w * w.w;
    }
    for (int o = 32; o > 0; o >>= 1) ss += __shfl_down(ss, o);
    __shared__ float red[4];
    int wid = threadIdx.x >> 6, lane = threadIdx.x & 63;
    if (lane == 0) red[wid] = ss;
    __syncthreads();
    if (threadIdx.x == 0) sc[row] = red[0] + red[1] + red[2] + red[3];
}

__global__ __launch_bounds__(256) void k_rank(const float* __restrict__ sc,
                                              int* __restrict__ flg, int s, int kk) {
    int b = blockIdx.x / s, i = blockIdx.x % s;
    const float* scb = sc + (size_t)b * s;
    float vi = scb[i];
    int cnt = 0;
    for (int j = threadIdx.x; j < s; j += 256) {
        float vj = scb[j];
        if (vj > vi || (vj == vi && j < i)) cnt++;
    }
    for (int o = 32; o > 0; o >>= 1) cnt += __shfl_down(cnt, o);
    __shared__ int red[4];
    int wid = threadIdx.x >> 6, lane = threadIdx.x & 63;
    if (lane == 0) red[wid] = cnt;
    __syncthreads();
    if (threadIdx.x == 0) flg[b * s + i] = ((red[0] + red[1] + red[2] + red[3]) < kk) ? 1 : 0;
}

__global__ void k_compact(const int* __restrict__ flg, int* __restrict__ idx, int s, int kk) {
    int b = blockIdx.x;
    if (threadIdx.x == 0) {
        int p = 0;
        for (int i = 0; i < s; i++)
            if (flg[b * s + i]) idx[b * kk + (p++)] = i;
    }
}

__global__ void k_gather(const float* __restrict__ Hin, const int* __restrict__ idx,
                         float* __restrict__ Hout, int s, int kk) {
    int row = blockIdx.x;
    int b = row / kk, p = row % kk;
    int i = idx[b * kk + p];
    const f4* src = (const f4*)(Hin + (size_t)(b * s + i) * DD);
    f4* dst = (f4*)(Hout + (size_t)row * DD);
    for (int t = threadIdx.x; t < DD / 4; t += blockDim.x) dst[t] = src[t];
}

__global__ void k_gather_mask(const int* __restrict__ Min, const int* __restrict__ idx,
                              int* __restrict__ Mout, int s, int kk) {
    int t = blockIdx.x * blockDim.x + threadIdx.x;
    if (t < BBATCH * kk) {
        int b = t / kk, p = t % kk;
        Mout[t] = Min[b * s + idx[b * kk + p]];
    }
}

// ---------------------------------------------------------------------------
extern "C" void kernel_launch(void* const* d_in, const int* in_sizes, int n_in,
                              void* d_out, int out_size, void* d_ws, size_t ws_size,
                              hipStream_t stream) {
    const int*   input_ids = (const int*)d_in[0];
    const int*   attn_mask = (const int*)d_in[1];
    const float* embed     = (const float*)d_in[2];
    const float* wq        = (const float*)d_in[3];
    const float* wk        = (const float*)d_in[4];
    const float* wv        = (const float*)d_in[5];
    const float* wo        = (const float*)d_in[6];
    const float* wg        = (const float*)d_in[7];
    const float* wu        = (const float*)d_in[8];
    const float* wd        = (const float*)d_in[9];
    const float* ln1       = (const float*)d_in[10];
    const float* ln2       = (const float*)d_in[11];
    const float* lnf       = (const float*)d_in[12];
    const float* lm_head   = (const float*)d_in[13];
    const float* scorer    = (const float*)d_in[14];

    float* ws = (float*)d_ws;
    const size_t R = (size_t)BBATCH * SSEQ * DD;
    const size_t MISC_FLOATS = 2 * SSEQ * 64 + 5 * (size_t)BBATCH * SSEQ + 1024;
    const size_t NEED_A = (14 * R + MISC_FLOATS) * 4;
    const bool bigws = (ws_size >= NEED_A);

    float* H0   = ws;
    float* H1   = ws + R;
    float* CQKV = ws + 2 * R;
    u16*   AH   = (u16*)(ws + 5 * R);
    u16*   AL   = AH + (size_t)4096 * DD;

    u16* QHp = (u16*)(ws + 6 * R);
    u16* QLp = QHp + (size_t)4096 * DD;
    u16* KHp = (u16*)(ws + 7 * R);
    u16* KLp = KHp + (size_t)4096 * DD;
    u16* VtH = (u16*)(ws + 8 * R);
    u16* VtL = VtH + (size_t)4096 * DD;
    u16* FH  = (u16*)(ws + 6 * R);
    u16* FL  = (u16*)(ws + 8 * R);
    u16* WH1 = (u16*)(ws + 10 * R);
    u16* WL1 = WH1 + (size_t)FFF * DD;
    u16* WH2 = (u16*)(ws + 12 * R);
    u16* WL2 = WH2 + (size_t)FFF * DD;
    u16* WDH = (u16*)(ws + 10 * R);
    u16* WDL = WDH + (size_t)DD * FFF;
    u16* WQKVH = (u16*)(ws + 10 * R);
    u16* WQKVL = WQKVH + (size_t)6144 * DD;

    u16* cWgH = (u16*)CQKV;
    u16* cWgL = cWgH + (size_t)2048 * DD;
    u16* cWuH = cWgL + (size_t)2048 * DD;
    u16* cWuL = cWuH + (size_t)2048 * DD;
    u16* cFH  = (u16*)(ws + 3 * R);
    u16* cFL  = cFH + (size_t)4096 * 2048;
    u16* cWdH = (u16*)(ws + 4 * R);
    u16* cWdL = cWdH + (size_t)2048 * DD;

    float* miscB = ws + (bigws ? 14 * R : 6 * R);
    float* COS = miscB;
    float* SIN = COS + SSEQ * 64;
    float* SC  = SIN + SSEQ * 64;
    int*   FLG = (int*)(SC + (size_t)BBATCH * SSEQ);
    int*   IDX = FLG + BBATCH * SSEQ;
    int*   M0  = IDX + BBATCH * SSEQ;
    int*   M1  = M0 + BBATCH * SSEQ;

    k_rope_table<<<(SSEQ * 64 + 255) / 256, 256, 0, stream>>>(COS, SIN);
    k_embed<<<BBATCH * SSEQ, 256, 0, stream>>>(input_ids, embed, H0);
    k_copy_int<<<(BBATCH * SSEQ + 255) / 256, 256, 0, stream>>>(attn_mask, M0, BBATCH * SSEQ);

    float* Hc = H0; float* Nc = H1;
    int*   Mc = M0; int*   Mt = M1;
    int s = SSEQ;

    for (int l = 0; l < LLAYERS; l++) {
        if (l == 1 || l == 2) {
            int pi = l - 1;
            int kk = s / 2;
            k_score<<<BBATCH * s, 256, 0, stream>>>(Hc, scorer + (size_t)pi * 2 * DD, SC);
            k_rank<<<BBATCH * s, 256, 0, stream>>>(SC, FLG, s, kk);
            k_compact<<<BBATCH, 64, 0, stream>>>(FLG, IDX, s, kk);
            k_gather<<<BBATCH * kk, 256, 0, stream>>>(Hc, IDX, Nc, s, kk);
            k_gather_mask<<<(BBATCH * kk + 255) / 256, 256, 0, stream>>>(Mc, IDX, Mt, s, kk);
            { float* t = Hc; Hc = Nc; Nc = t; }
            { int* t = Mc; Mc = Mt; Mt = t; }
            s = kk;
        }
        int rows = BBATCH * s;
        const bool hiP = (l < 2);
        const int wlo = hiP ? 1 : 0;
        const float* Wq = wq + (size_t)l * DD * DD;
        const float* Wk = wk + (size_t)l * DD * DD;
        const float* Wv = wv + (size_t)l * DD * DD;
        const float* Wo = wo + (size_t)l * DD * DD;
        const float* Wg = wg + (size_t)l * DD * FFF;
        const float* Wu = wu + (size_t)l * DD * FFF;
        const float* Wd = wd + (size_t)l * FFF * DD;
        const float* L1 = ln1 + (size_t)l * DD;
        const float* L2 = ln2 + (size_t)l * DD;

        dim3 gWd(DD / 64, DD / 64);

        // ---- QKV projection (fused) ----
        k_rmsnorm_cvt<<<rows, 256, 0, stream>>>(Hc, L1, AH, AL);
        if (bigws) {
            k_cvt_w<<<gWd, 256, 0, stream>>>(Wq, WQKVH, WQKVL, DD, DD, 0, 0, wlo);
            k_cvt_w<<<gWd, 256, 0, stream>>>(Wk, WQKVH, WQKVL, DD, DD, 0, 2048, wlo);
            k_cvt_w<<<gWd, 256, 0, stream>>>(Wv, WQKVH, WQKVL, DD, DD, 0, 4096, wlo);
            if (rows >= 2048) {
                dim3 gQKV(6144 / 256, rows / 256);
                if (hiP) k_bg256<3,0,0><<<gQKV,512,0,stream>>>(AH,AL,WQKVH,WQKVL,CQKV,nullptr,nullptr,nullptr,nullptr,rows,6144,DD,DD);
                else     k_bg256<1,0,0><<<gQKV,512,0,stream>>>(AH,AL,WQKVH,WQKVL,CQKV,nullptr,nullptr,nullptr,nullptr,rows,6144,DD,DD);
            } else {
                dim3 gQKV(6144 / 128, rows / 128);
                k_bgemm<1,0,0><<<gQKV,256,0,stream>>>(AH,AL,WQKVH,WQKVL,nullptr,nullptr,nullptr,CQKV,nullptr,nullptr,rows,6144,DD);
            }
        } else {
            u16* WtH = (u16*)Nc;
            u16* WtL = WtH + (size_t)DD * DD;
            dim3 gG(DD / 128, rows / 128);
            const float* Wqkv[3] = {Wq, Wk, Wv};
            for (int q3 = 0; q3 < 3; q3++) {
                k_cvt_w<<<gWd, 256, 0, stream>>>(Wqkv[q3], WtH, WtL, DD, DD, 0, 0, wlo);
                float* Cb = CQKV + q3 * 2048;
                if (hiP) k_bgemm<3,0,0><<<gG,256,0,stream>>>(AH,AL,WtH,WtL,nullptr,nullptr,nullptr,Cb,nullptr,nullptr,rows,6144,DD);
                else     k_bgemm<1,0,0><<<gG,256,0,stream>>>(AH,AL,WtH,WtL,nullptr,nullptr,nullptr,Cb,nullptr,nullptr,rows,6144,DD);
            }
        }

        // ---- attention ----
        if (bigws) {
            k_cvt_qkr<<<rows, 256, 0, stream>>>(CQKV, COS, SIN, QHp, QLp, KHp, KLp, s);
            k_cvt_vt<<<dim3(s / 64, BBATCH * HH), 256, 0, stream>>>(CQKV, VtH, VtL, s);
            if (hiP) k_attn_mfma<3><<<dim3(s / 128, BBATCH * HH), 256, 0, stream>>>(
                         QHp, QLp, KHp, KLp, VtH, VtL, Mc, AH, AL, s);
            else     k_attn_mfma<1><<<dim3(s / 128, BBATCH * HH), 256, 0, stream>>>(
                         QHp, QLp, KHp, KLp, VtH, VtL, Mc, AH, AL, s);
        } else {
            k_rope<<<rows * HH, 64, 0, stream>>>(CQKV, COS, SIN, s, 6144);
            k_attn_f32<<<dim3(s / 64, BBATCH * HH), 256, 0, stream>>>(
                CQKV, CQKV + 2048, CQKV + 4096, Mc, AH, AL, s, 6144);
        }

        // ---- wo projection + residual ----
        {
            u16* WtH = bigws ? WQKVH : (u16*)Nc;
            u16* WtL = bigws ? (WQKVH + (size_t)DD * DD) : ((u16*)Nc + (size_t)DD * DD);
            k_cvt_w<<<gWd, 256, 0, stream>>>(Wo, WtH, WtL, DD, DD, 0, 0, wlo);
            if (bigws && hiP) {
                int SK = (rows >= 4096) ? 2 : 4;
                float* P = ws + 2 * R;
                dim3 g(DD / 256, rows / 256, SK);
                k_bg256<3,0,0><<<g, 512, 0, stream>>>(AH, AL, WtH, WtL, P,
                                                      nullptr, nullptr, nullptr, nullptr,
                                                      rows, DD, DD / SK, DD);
                long len = (long)rows * DD;
                k_addN<<<(len / 4 + 255) / 256, 256, 0, stream>>>(Hc, P, len, SK);
            } else {
                dim3 gG(DD / 128, rows / 128);
                if (hiP) k_bgemm<3,1,0><<<gG,256,0,stream>>>(AH,AL,WtH,WtL,nullptr,nullptr,Hc,Hc,nullptr,nullptr,rows,DD,DD);
                else     k_bgemm<1,1,0><<<gG,256,0,stream>>>(AH,AL,WtH,WtL,nullptr,nullptr,Hc,Hc,nullptr,nullptr,rows,DD,DD);
            }
        }

        // ---- MLP ----
        k_rmsnorm_cvt<<<rows, 256, 0, stream>>>(Hc, L2, AH, AL);
        if (bigws && rows >= 2048) {
            k_cvt_w<<<dim3(FFF / 64, DD / 64), 256, 0, stream>>>(Wg, WH1, WL1, DD, FFF, 0, 0, wlo);
            k_cvt_w<<<dim3(FFF / 64, DD / 64), 256, 0, stream>>>(Wu, WH2, WL2, DD, FFF, 0, 0, wlo);
            u16* Gh = (l == 0) ? (u16*)(ws + R) : (u16*)(ws + 2 * R);
            u16* Gl = (u16*)(ws + 3 * R);
            dim3 gMLP(FFF / 256, rows / 256);
            if (hiP) {
                k_bg256<3,1,0><<<gMLP,512,0,stream>>>(AH,AL,WH1,WL1,nullptr,Gh,Gl,nullptr,nullptr,rows,FFF,DD,DD);
                k_bg256<3,1,1><<<gMLP,512,0,stream>>>(AH,AL,WH2,WL2,nullptr,FH,FL,Gh,Gl,rows,FFF,DD,DD);
            } else {
                k_bg256<1,1,0><<<gMLP,512,0,stream>>>(AH,AL,WH1,WL1,nullptr,Gh,Gl,nullptr,nullptr,rows,FFF,DD,DD);
                k_bg256<1,1,1><<<gMLP,512,0,stream>>>(AH,AL,WH2,WL2,nullptr,FH,FL,Gh,Gl,rows,FFF,DD,DD);
            }
            k_cvt_w<<<dim3(DD / 64, FFF / 64), 256, 0, stream>>>(Wd, WDH, WDL, FFF, DD, 0, 0, wlo);
            int SK = (rows >= 4096) ? 2 : 4;
            float* P = ws + 2 * R;
            dim3 gD(DD / 256, rows / 256, SK);
            if (hiP) k_bg256<3,0,0><<<gD,512,0,stream>>>(FH,FL,WDH,WDL,P,nullptr,nullptr,nullptr,nullptr,rows,DD,FFF/SK,FFF);
            else     k_bg256<1,0,0><<<gD,512,0,stream>>>(FH,FL,WDH,WDL,P,nullptr,nullptr,nullptr,nullptr,rows,DD,FFF/SK,FFF);
            long len = (long)rows * DD;
            k_addN<<<(len / 4 + 255) / 256, 256, 0, stream>>>(Hc, P, len, SK);
        } else if (bigws) {
            k_cvt_w<<<dim3(FFF / 64, DD / 64), 256, 0, stream>>>(Wg, WH1, WL1, DD, FFF, 0, 0, wlo);
            k_cvt_w<<<dim3(FFF / 64, DD / 64), 256, 0, stream>>>(Wu, WH2, WL2, DD, FFF, 0, 0, wlo);
            k_bgemm<1,0,1><<<dim3(FFF/128, rows/128),256,0,stream>>>(AH,AL,WH1,WL1,WH2,WL2,nullptr,nullptr,FH,FL,rows,FFF,DD);
            k_cvt_w<<<dim3(DD / 64, FFF / 64), 256, 0, stream>>>(Wd, WDH, WDL, FFF, DD, 0, 0, wlo);
            k_bgemm<1,1,0><<<dim3(DD/128, rows/128),256,0,stream>>>(FH,FL,WDH,WDL,nullptr,nullptr,Hc,Hc,nullptr,nullptr,rows,DD,FFF);
        } else {
            for (int ffc = 0; ffc < FFF; ffc += 2048) {
                k_cvt_w<<<dim3(2048 / 64, DD / 64), 256, 0, stream>>>(Wg, cWgH, cWgL, DD, FFF, ffc, 0, wlo);
                k_cvt_w<<<dim3(2048 / 64, DD / 64), 256, 0, stream>>>(Wu, cWuH, cWuL, DD, FFF, ffc, 0, wlo);
                if (hiP) k_bgemm<3,0,1><<<dim3(16, rows/128),256,0,stream>>>(AH,AL,cWgH,cWgL,cWuH,cWuL,nullptr,nullptr,cFH,cFL,rows,2048,DD);
                else     k_bgemm<1,0,1><<<dim3(16, rows/128),256,0,stream>>>(AH,AL,cWgH,cWgL,cWuH,cWuL,nullptr,nullptr,cFH,cFL,rows,2048,DD);
                k_cvt_w<<<dim3(DD / 64, 2048 / 64), 256, 0, stream>>>(Wd + (size_t)ffc * DD, cWdH, cWdL, 2048, DD, 0, 0, wlo);
                if (hiP) k_bgemm<3,1,0><<<dim3(DD/128, rows/128),256,0,stream>>>(cFH,cFL,cWdH,cWdL,nullptr,nullptr,Hc,Hc,nullptr,nullptr,rows,DD,2048);
                else     k_bgemm<1,1,0><<<dim3(DD/128, rows/128),256,0,stream>>>(cFH,cFL,cWdH,cWdL,nullptr,nullptr,Hc,Hc,nullptr,nullptr,rows,DD,2048);
            }
        }
    }

    // ---- final rmsnorm + lm_head ----
    int rows = BBATCH * s;   // 1024
    u16* AHf = (u16*)Nc;
    u16* ALf = AHf + (size_t)rows * DD;
    u16* LmH = bigws ? (u16*)(ws + 6 * R) : (u16*)CQKV;
    k_rmsnorm_cvt<<<rows, 256, 0, stream>>>(Hc, lnf, AHf, ALf);
    k_cvt_w<<<dim3(VV / 64, DD / 64), 256, 0, stream>>>(lm_head, LmH, LmH, DD, VV, 0, 0, 0);
    if (bigws) {
        k_bg256<1,0,0><<<dim3(VV / 256, rows / 256), 512, 0, stream>>>(
            AHf, ALf, LmH, LmH, (float*)d_out, nullptr, nullptr, nullptr, nullptr,
            rows, VV, DD, DD);
    } else {
        k_bgemm<1,0,0><<<dim3(VV / 128, rows / 128), 256, 0, stream>>>(
            AHf, ALf, LmH, LmH, nullptr, nullptr, nullptr, (float*)d_out,
            nullptr, nullptr, rows, VV, DD);
    }
}

// Round 17
// 4317.935 us; speedup vs baseline: 1.0938x; 1.0488x over previous
//
#include <hip/hip_runtime.h>
#include <math.h>

// ---------------------------------------------------------------------------
// SDTP forward, round 17 = r14/r16 + split-K bg256 for L2/L3 wo & down-proj
// (they ran at 128 blocks = half GPU). SK = 8192/rows -> every wo/down GEMM
// launches 256 blocks. Deterministic partials + k_addN (reorder ~1e-6 only).
// ---------------------------------------------------------------------------

#define DD 2048
#define HH 16
#define DHH 128
#define FFF 8192
#define BBATCH 2
#define SSEQ 2048
#define VV 32000
#define LLAYERS 4

typedef float4 f4;
typedef __attribute__((ext_vector_type(8))) short short8;
typedef __attribute__((ext_vector_type(4))) float f32x4;
typedef unsigned short u16;

__device__ inline u16 bf16rne(float x) {
    unsigned u = __float_as_uint(x);
    unsigned r = (u + 0x7FFFu + ((u >> 16) & 1u)) >> 16;
    return (u16)r;
}
__device__ inline float bf16tof(u16 h) {
    return __uint_as_float(((unsigned)h) << 16);
}

__device__ __forceinline__ void gload16(const u16* g, u16* l) {
    __builtin_amdgcn_global_load_lds(
        (const __attribute__((address_space(1))) unsigned int*)g,
        (__attribute__((address_space(3))) unsigned int*)l, 16, 0, 0);
}

#define BARRIER() do { asm volatile("" ::: "memory"); \
    __builtin_amdgcn_s_barrier(); asm volatile("" ::: "memory"); } while (0)

// bijective XCD-aware block swizzle (m204), COLUMN-major orig
__device__ __forceinline__ void xcd_swz(int& bx, int& by) {
    int gy = gridDim.y;
    int nwg = gridDim.x * gy;
    int orig = bx * gy + by;
    int q = nwg >> 3, r = nwg & 7;
    int xcd = orig & 7, loc = orig >> 3;
    int swz = (xcd < r ? xcd * (q + 1) : r * (q + 1) + (xcd - r) * q) + loc;
    bx = swz / gy;
    by = swz % gy;
}

// ---------------- embedding / copies ----------------
__global__ void k_embed(const int* __restrict__ ids, const float* __restrict__ emb,
                        float* __restrict__ out) {
    int row = blockIdx.x;
    int id  = ids[row];
    const f4* src = (const f4*)(emb + (size_t)id * DD);
    f4*       dst = (f4*)(out + (size_t)row * DD);
    for (int i = threadIdx.x; i < DD / 4; i += blockDim.x) dst[i] = src[i];
}

__global__ void k_copy_int(const int* __restrict__ src, int* __restrict__ dst, int n) {
    int i = blockIdx.x * blockDim.x + threadIdx.x;
    if (i < n) dst[i] = src[i];
}

// H[i] += sum_z P[z*len + i]
__global__ void k_addN(float* __restrict__ H, const float* __restrict__ P,
                       long len, int nparts) {
    long i = (long)blockIdx.x * 256 + threadIdx.x;
    if (i >= len / 4) return;
    f4 h = ((f4*)H)[i];
    for (int z = 0; z < nparts; z++) {
        f4 p = ((const f4*)(P + (size_t)z * len))[i];
        h.x += p.x; h.y += p.y; h.z += p.z; h.w += p.w;
    }
    ((f4*)H)[i] = h;
}

// ---------------- rmsnorm -> bf16 hi/lo planes ----------------
__global__ __launch_bounds__(256) void k_rmsnorm_cvt(const float* __restrict__ x,
                                                     const float* __restrict__ w,
                                                     u16* __restrict__ OH,
                                                     u16* __restrict__ OL) {
    int row = blockIdx.x;
    const float* xr = x + (size_t)row * DD;
    float ss = 0.f;
    for (int i = threadIdx.x; i < DD / 4; i += blockDim.x) {
        f4 v = ((const f4*)xr)[i];
        ss += v.x * v.x + v.y * v.y + v.z * v.z + v.w * v.w;
    }
    for (int o = 32; o > 0; o >>= 1) ss += __shfl_down(ss, o);
    __shared__ float red[4];
    int wid = threadIdx.x >> 6, lane = threadIdx.x & 63;
    if (lane == 0) red[wid] = ss;
    __syncthreads();
    float tot = red[0] + red[1] + red[2] + red[3];
    float inv = 1.0f / sqrtf(tot / (float)DD + 1e-6f);
    for (int i = threadIdx.x; i < DD / 4; i += blockDim.x) {
        f4 v = ((const f4*)xr)[i];
        f4 wv = ((const f4*)w)[i];
        float o[4];
        o[0] = v.x * wv.x * inv; o[1] = v.y * wv.y * inv;
        o[2] = v.z * wv.z * inv; o[3] = v.w * wv.w * inv;
        ushort4 hv, lv;
        u16* hp = (u16*)&hv; u16* lp = (u16*)&lv;
#pragma unroll
        for (int j = 0; j < 4; j++) {
            u16 h = bf16rne(o[j]);
            hp[j] = h;
            lp[j] = bf16rne(o[j] - bf16tof(h));
        }
        *(ushort4*)&OH[(size_t)row * DD + i * 4] = hv;
        *(ushort4*)&OL[(size_t)row * DD + i * 4] = lv;
    }
}

// ---------------- weight transpose+convert: W[K][N] -> planes [n][K] -------
__global__ __launch_bounds__(256) void k_cvt_w(const float* __restrict__ W,
                                               u16* __restrict__ WtH,
                                               u16* __restrict__ WtL,
                                               int K, int N, int nc0, int dn0,
                                               int writeLo) {
    __shared__ float T[64][65];
    int tid = threadIdx.x;
    int n0g = nc0 + blockIdx.x * 64;
    int k0  = blockIdx.y * 64;
#pragma unroll
    for (int it = 0; it < 4; it++) {
        int r = it * 16 + (tid >> 4);
        int c4 = (tid & 15) * 4;
        f4 v = *(const f4*)(W + (size_t)(k0 + r) * N + n0g + c4);
        T[r][c4 + 0] = v.x; T[r][c4 + 1] = v.y;
        T[r][c4 + 2] = v.z; T[r][c4 + 3] = v.w;
    }
    __syncthreads();
    int nl = tid >> 2;
    int ks = (tid & 3) * 16;
    u16 hi[16], lo[16];
#pragma unroll
    for (int j = 0; j < 16; j++) {
        float v = T[ks + j][nl];
        u16 h = bf16rne(v);
        hi[j] = h;
        lo[j] = bf16rne(v - bf16tof(h));
    }
    size_t base = (size_t)(dn0 + blockIdx.x * 64 + nl) * K + k0 + ks;
    *(short8*)&WtH[base]     = *(short8*)&hi[0];
    *(short8*)&WtH[base + 8] = *(short8*)&hi[8];
    if (writeLo) {
        *(short8*)&WtL[base]     = *(short8*)&lo[0];
        *(short8*)&WtL[base + 8] = *(short8*)&lo[8];
    }
}

// ---------------- bf16 MFMA GEMM, m97 structure (128x128) ----------------
template <int PASSES, int RES, int DUAL>
__global__ __launch_bounds__(256, 2) void k_bgemm(const u16* __restrict__ AH,
                                                  const u16* __restrict__ AL,
                                                  const u16* __restrict__ B1H,
                                                  const u16* __restrict__ B1L,
                                                  const u16* __restrict__ B2H,
                                                  const u16* __restrict__ B2L,
                                                  const float* __restrict__ Rsrc,
                                                  float* __restrict__ C,
                                                  u16* __restrict__ OH,
                                                  u16* __restrict__ OL,
                                                  int M, int ldC, int K) {
    constexpr int NW = DUAL ? 2 : 1;
    __shared__ u16 As[128 * 32];
    __shared__ u16 Bs[NW][128 * 32];
    int tid = threadIdx.x;
    int bx = blockIdx.x, by = blockIdx.y;
    xcd_swz(bx, by);
    int m0 = by * 128, n0 = bx * 128;
    int lane = tid & 63, w = tid >> 6;
    int wm = w >> 1, wn = w & 1;
    int lr = lane & 15, lq = lane >> 4;
    int grow = lane >> 2;
    int gcol = (lane & 3) * 8;

    f32x4 acc[NW][4][4];
#pragma unroll
    for (int u = 0; u < NW; u++)
#pragma unroll
        for (int i = 0; i < 4; i++)
#pragma unroll
            for (int j = 0; j < 4; j++)
#pragma unroll
                for (int r = 0; r < 4; r++) acc[u][i][j][r] = 0.f;

    const int KT = PASSES * K;
    for (int kb = 0; kb < KT; kb += 32) {
        int p  = (PASSES > 1) ? ((kb >= 2 * K) ? 2 : ((kb >= K) ? 1 : 0)) : 0;
        int ks = kb - p * K;
        const u16* Ab = ((p == 2) ? AL  : AH)  + (size_t)(m0 + w * 32) * K + ks;
        const u16* Bb = ((p == 1) ? B1L : B1H) + (size_t)(n0 + w * 32) * K + ks;
        __syncthreads();
        gload16(Ab + (size_t)grow * K + gcol,        &As[w * 1024]);
        gload16(Ab + (size_t)(grow + 16) * K + gcol, &As[w * 1024 + 512]);
        gload16(Bb + (size_t)grow * K + gcol,        &Bs[0][w * 1024]);
        gload16(Bb + (size_t)(grow + 16) * K + gcol, &Bs[0][w * 1024 + 512]);
        if constexpr (DUAL) {
            const u16* B2b = ((p == 1) ? B2L : B2H) + (size_t)(n0 + w * 32) * K + ks;
            gload16(B2b + (size_t)grow * K + gcol,        &Bs[1][w * 1024]);
            gload16(B2b + (size_t)(grow + 16) * K + gcol, &Bs[1][w * 1024 + 512]);
        }
        __syncthreads();
        short8 a[4];
#pragma unroll
        for (int i = 0; i < 4; i++)
            a[i] = *(const short8*)&As[(wm * 64 + i * 16 + lr) * 32 + lq * 8];
#pragma unroll
        for (int u = 0; u < NW; u++) {
#pragma unroll
            for (int j = 0; j < 4; j++) {
                short8 b = *(const short8*)&Bs[u][(wn * 64 + j * 16 + lr) * 32 + lq * 8];
#pragma unroll
                for (int i = 0; i < 4; i++)
                    acc[u][i][j] = __builtin_amdgcn_mfma_f32_16x16x32_bf16(
                        a[i], b, acc[u][i][j], 0, 0, 0);
            }
        }
    }
#pragma unroll
    for (int i = 0; i < 4; i++) {
#pragma unroll
        for (int j = 0; j < 4; j++) {
            int gm = m0 + wm * 64 + i * 16 + lq * 4;
            int gn = n0 + wn * 64 + j * 16 + lr;
#pragma unroll
            for (int r = 0; r < 4; r++) {
                size_t off = (size_t)(gm + r) * ldC + gn;
                if constexpr (DUAL) {
                    float g = acc[0][i][j][r], uu = acc[1][i][j][r];
                    float v = g / (1.0f + expf(-g)) * uu;
                    u16 h = bf16rne(v);
                    OH[off] = h;
                    OL[off] = bf16rne(v - bf16tof(h));
                } else {
                    float v = acc[0][i][j][r];
                    if constexpr (RES) v += Rsrc[off];
                    C[off] = v;
                }
            }
        }
    }
}

// ---------------- 256x256-tile GEMM, batch-issue tile schedule ----------------
// EPI: epilogue reads gate planes GEH/GEL at off, v = silu(g) * acc (fp32 u).
template <int PASSES, int PLANE, int EPI>
__global__ __launch_bounds__(512, 2) void k_bg256(const u16* __restrict__ AH,
                                                  const u16* __restrict__ AL,
                                                  const u16* __restrict__ BH,
                                                  const u16* __restrict__ BL,
                                                  float* __restrict__ C,
                                                  u16* __restrict__ OH,
                                                  u16* __restrict__ OL,
                                                  const u16* __restrict__ GEH,
                                                  const u16* __restrict__ GEL,
                                                  int M, int ldC, int K, int ld) {
    __shared__ u16 SM[65536];   // 128 KB: 2 bufs x 64KB
    int tid = threadIdx.x;
    int bx = blockIdx.x, by = blockIdx.y;
    xcd_swz(bx, by);
    {   // split-K part select
        size_t zo = (size_t)blockIdx.z * K;
        AH += zo; BH += zo;
        if constexpr (PASSES > 1) { AL += zo; BL += zo; }
        if constexpr (!PLANE) C += (size_t)blockIdx.z * ((size_t)M * ldC);
    }
    int m0 = by * 256, n0 = bx * 256;
    int w = tid >> 6, lane = tid & 63;
    int wm = w >> 2, wn = w & 3;
    int lr = lane & 15, lq = lane >> 4;

    f32x4 acc[8][4];
#pragma unroll
    for (int i = 0; i < 8; i++)
#pragma unroll
        for (int j = 0; j < 4; j++)
#pragma unroll
            for (int r = 0; r < 4; r++) acc[i][j][r] = 0.f;

    auto ASRC = [&](int T) -> const u16* {
        int kb = T * 64;
        if (PASSES > 1) {
            if (kb >= 2 * K) return AL + (kb - 2 * K);
            if (kb >= K)     return AH + (kb - K);
        }
        return AH + kb;
    };
    auto BSRC = [&](int T) -> const u16* {
        int kb = T * 64;
        if (PASSES > 1) {
            if (kb >= 2 * K) return BH + (kb - 2 * K);
            if (kb >= K)     return BL + (kb - K);
        }
        return BH + kb;
    };
    int srr = lane >> 3;
    int scc = ((lane & 7) ^ srr) * 8;   // pre-swizzled source column
    auto STAGE_A = [&](int T, int h, int buf) {
        const u16* s = ASRC(T) + (size_t)(m0 + h * 128 + w * 16 + srr) * ld + scc;
        u16* d = SM + buf * 32768 + h * 8192 + w * 16 * 64;
        gload16(s, d);
        gload16(s + (size_t)8 * ld, d + 8 * 64);
    };
    auto STAGE_B = [&](int T, int h, int buf) {
        const u16* s = BSRC(T) + (size_t)(n0 + h * 128 + w * 16 + srr) * ld + scc;
        u16* d = SM + buf * 32768 + 16384 + h * 8192 + w * 16 * 64;
        gload16(s, d);
        gload16(s + (size_t)8 * ld, d + 8 * 64);
    };
    auto RD_A = [&](const u16* SMb, int MH, short8 (&aF)[4][2]) {
        const u16* Ab = SMb + MH * 8192;
#pragma unroll
        for (int i = 0; i < 4; i++)
#pragma unroll
            for (int kk = 0; kk < 2; kk++)
                aF[i][kk] = *(const short8*)&Ab[(wm * 64 + i * 16 + lr) * 64 +
                                                (((kk * 4 + lq) ^ (lr & 7)) * 8)];
    };
    auto RD_B = [&](const u16* SMb, int NH, short8 (&bF)[2][2]) {
        const u16* Bb = SMb + 16384 + NH * 8192;
#pragma unroll
        for (int j = 0; j < 2; j++)
#pragma unroll
            for (int kk = 0; kk < 2; kk++)
                bF[j][kk] = *(const short8*)&Bb[(wn * 32 + j * 16 + lr) * 64 +
                                                (((kk * 4 + lq) ^ (lr & 7)) * 8)];
    };

    const int NT = (PASSES * K) >> 6;
    STAGE_A(0, 0, 0); STAGE_B(0, 0, 0);
    STAGE_A(0, 1, 0); STAGE_B(0, 1, 0);
    asm volatile("s_waitcnt vmcnt(0)" ::: "memory");
    BARRIER();

    for (int T = 0; T < NT; T++) {
        int cur = T & 1;
        const u16* SMb = SM + cur * 32768;
        short8 a0[4][2], a1[4][2], b0[2][2], b1[2][2];
        if (T + 1 < NT) { STAGE_A(T + 1, 0, cur ^ 1); STAGE_B(T + 1, 0, cur ^ 1); }
        RD_A(SMb, 0, a0);
        RD_B(SMb, 0, b0);
        if (T + 1 < NT) { STAGE_A(T + 1, 1, cur ^ 1); STAGE_B(T + 1, 1, cur ^ 1); }
        RD_B(SMb, 1, b1);
        RD_A(SMb, 1, a1);
        __builtin_amdgcn_s_setprio(1);
#pragma unroll
        for (int kk = 0; kk < 2; kk++)
#pragma unroll
            for (int j = 0; j < 2; j++)
#pragma unroll
                for (int i = 0; i < 4; i++)
                    acc[i][j] = __builtin_amdgcn_mfma_f32_16x16x32_bf16(
                        a0[i][kk], b0[j][kk], acc[i][j], 0, 0, 0);
#pragma unroll
        for (int kk = 0; kk < 2; kk++)
#pragma unroll
            for (int j = 0; j < 2; j++)
#pragma unroll
                for (int i = 0; i < 4; i++)
                    acc[i][2 + j] = __builtin_amdgcn_mfma_f32_16x16x32_bf16(
                        a0[i][kk], b1[j][kk], acc[i][2 + j], 0, 0, 0);
#pragma unroll
        for (int kk = 0; kk < 2; kk++)
#pragma unroll
            for (int j = 0; j < 2; j++)
#pragma unroll
                for (int i = 0; i < 4; i++)
                    acc[4 + i][j] = __builtin_amdgcn_mfma_f32_16x16x32_bf16(
                        a1[i][kk], b0[j][kk], acc[4 + i][j], 0, 0, 0);
#pragma unroll
        for (int kk = 0; kk < 2; kk++)
#pragma unroll
            for (int j = 0; j < 2; j++)
#pragma unroll
                for (int i = 0; i < 4; i++)
                    acc[4 + i][2 + j] = __builtin_amdgcn_mfma_f32_16x16x32_bf16(
                        a1[i][kk], b1[j][kk], acc[4 + i][2 + j], 0, 0, 0);
        __builtin_amdgcn_s_setprio(0);
        if (T + 1 < NT) {
            asm volatile("s_waitcnt vmcnt(0)" ::: "memory");
            BARRIER();
        }
    }

#pragma unroll
    for (int i16 = 0; i16 < 8; i16++) {
#pragma unroll
        for (int jj = 0; jj < 4; jj++) {
            int gm = m0 + (i16 >> 2) * 128 + wm * 64 + (i16 & 3) * 16 + lq * 4;
            int gn = n0 + (jj >> 1) * 128 + wn * 32 + (jj & 1) * 16 + lr;
#pragma unroll
            for (int r = 0; r < 4; r++) {
                size_t off = (size_t)(gm + r) * ldC + gn;
                float v = acc[i16][jj][r];
                if constexpr (PLANE) {
                    if constexpr (EPI) {
                        float g = bf16tof(GEH[off]) + bf16tof(GEL[off]);
                        v = g / (1.0f + expf(-g)) * v;
                    }
                    u16 h = bf16rne(v);
                    OH[off] = h;
                    OL[off] = bf16rne(v - bf16tof(h));
                } else {
                    C[off] = v;
                }
            }
        }
    }
}

// ---------------- RoPE ----------------
__global__ void k_rope_table(float* __restrict__ cosT, float* __restrict__ sinT) {
    int idx = blockIdx.x * blockDim.x + threadIdx.x;
    if (idx >= SSEQ * 64) return;
    int pos = idx >> 6, d = idx & 63;
    float p   = (float)pow(10000.0, (double)d * (1.0 / 64.0));
    float inv = 1.0f / p;
    float ang = (float)pos * inv;
    cosT[idx] = (float)cos((double)ang);
    sinT[idx] = (float)sin((double)ang);
}

// tier-D only: in-place rotate Q,K of CQKV
__global__ void k_rope(float* __restrict__ C,
                       const float* __restrict__ cosT, const float* __restrict__ sinT,
                       int s, int ld) {
    int bi = blockIdx.x;
    int h = bi % HH;
    int i = (bi / HH) % s;
    size_t base = (size_t)(bi / HH) * ld + h * DHH;
    int d = threadIdx.x;
    float c  = cosT[i * 64 + d];
    float sn = sinT[i * 64 + d];
    float x1 = C[base + d], x2 = C[base + 64 + d];
    C[base + d]      = x1 * c - x2 * sn;
    C[base + 64 + d] = x1 * sn + x2 * c;
    x1 = C[base + 2048 + d]; x2 = C[base + 2048 + 64 + d];
    C[base + 2048 + d]      = x1 * c - x2 * sn;
    C[base + 2048 + 64 + d] = x1 * sn + x2 * c;
}

// ---------------- fused RoPE + Q/K fp32 -> bf16 hi/lo planes ----------------
__global__ __launch_bounds__(256) void k_cvt_qkr(const float* __restrict__ C,
                                                 const float* __restrict__ cosT,
                                                 const float* __restrict__ sinT,
                                                 u16* __restrict__ QHp, u16* __restrict__ QLp,
                                                 u16* __restrict__ KHp, u16* __restrict__ KLp,
                                                 int s) {
    int row = blockIdx.x;
    int i = row % s;
    int c = threadIdx.x * 8;
    int d = c & 127;
    int hi2 = (d >= 64) ? 1 : 0;
    int dd = d - hi2 * 64;
    const float* tb = cosT + (size_t)i * 64;
    const float* ts = sinT + (size_t)i * 64;
#pragma unroll
    for (int sec = 0; sec < 2; sec++) {
        const float* src = C + (size_t)row * 6144 + sec * 2048;
        int base1 = c - hi2 * 64;
        float o[8];
#pragma unroll
        for (int q = 0; q < 2; q++) {
            f4 v1 = *(const f4*)(src + base1 + q * 4);
            f4 v2 = *(const f4*)(src + base1 + 64 + q * 4);
            float a1[4] = {v1.x, v1.y, v1.z, v1.w};
            float a2[4] = {v2.x, v2.y, v2.z, v2.w};
#pragma unroll
            for (int e = 0; e < 4; e++) {
                float cc = tb[dd + q * 4 + e];
                float sn = ts[dd + q * 4 + e];
                o[q * 4 + e] = hi2 ? (a1[e] * sn + a2[e] * cc)
                                   : (a1[e] * cc - a2[e] * sn);
            }
        }
        u16 hbuf[8], lbuf[8];
#pragma unroll
        for (int e = 0; e < 8; e++) {
            u16 h = bf16rne(o[e]);
            hbuf[e] = h;
            lbuf[e] = bf16rne(o[e] - bf16tof(h));
        }
        u16* dh = (sec ? KHp : QHp) + (size_t)row * 2048 + c;
        u16* dl = (sec ? KLp : QLp) + (size_t)row * 2048 + c;
        *(short8*)dh = *(short8*)&hbuf[0];
        *(short8*)dl = *(short8*)&lbuf[0];
    }
}

// ---------------- V -> transposed swizzled planes Vt[b*h][128][s] ----------
__global__ __launch_bounds__(256) void k_cvt_vt(const float* __restrict__ C,
                                                u16* __restrict__ VtH,
                                                u16* __restrict__ VtL, int s) {
    __shared__ float T[64][132];
    int bh = blockIdx.y;
    int h = bh & 15, b = bh >> 4;
    int kv0 = blockIdx.x * 64;
    int t = threadIdx.x;
#pragma unroll
    for (int it = 0; it < 8; it++) {
        int kv = it * 8 + (t >> 5);
        int c4 = (t & 31) * 4;
        f4 v = *(const f4*)(C + (size_t)((size_t)b * s + kv0 + kv) * 6144 + 4096 + h * 128 + c4);
        T[kv][c4 + 0] = v.x; T[kv][c4 + 1] = v.y;
        T[kv][c4 + 2] = v.z; T[kv][c4 + 3] = v.w;
    }
    __syncthreads();
    int d = t >> 1, seg = t & 1;
    size_t base = ((size_t)bh * 128 + d) * s + kv0 + seg * 32;
#pragma unroll
    for (int g = 0; g < 4; g++) {
        u16 h8[8], l8[8];
#pragma unroll
        for (int e = 0; e < 8; e++) {
            float v = T[seg * 32 + g * 8 + e][d];
            u16 hh = bf16rne(v);
            h8[e] = hh;
            l8[e] = bf16rne(v - bf16tof(hh));
        }
        int gp = (g ^ ((d >> 1) & 3)) * 8;
        *(short8*)&VtH[base + gp] = *(short8*)&h8[0];
        *(short8*)&VtL[base + gp] = *(short8*)&l8[0];
    }
}

// ---------------- MFMA flash attention (QBLK=128, pipelined, bh-chunked) ----
template <int PASSES>
__global__ __launch_bounds__(256, 2) void k_attn_mfma(
        const u16* __restrict__ QHp, const u16* __restrict__ QLp,
        const u16* __restrict__ KHp, const u16* __restrict__ KLp,
        const u16* __restrict__ VtH, const u16* __restrict__ VtL,
        const int* __restrict__ mask,
        u16* __restrict__ OH, u16* __restrict__ OL, int s) {
    constexpr int BUFU = (PASSES > 1) ? 16384 : 8192;
    constexpr int VOFF = (PASSES > 1) ? 8192 : 4096;
    __shared__ u16 SM[2 * BUFU + 5120];
    int tid = threadIdx.x, lane = tid & 63, w = tid >> 6;
    int lr = lane & 15, lq = lane >> 4;
    int grow = lane >> 2;
    int sgcol = (((lane & 3) ^ ((lane >> 3) & 3))) * 8;
    int gcol  = (lane & 3) * 8;
    int rc = (lq ^ ((lr >> 1) & 3)) * 8;
    int gx = gridDim.x;
    int NB = gx * gridDim.y;
    int orig = blockIdx.y * gx + blockIdx.x;
    int qq = NB >> 3, rr = NB & 7;
    int xcd = orig & 7, loc = orig >> 3;
    int swz = (xcd < rr ? xcd * (qq + 1) : rr * (qq + 1) + (xcd - rr) * qq) + loc;
    int bh = swz / gx;
    int qt = gx - 1 - (swz % gx);
    int h = bh & 15, b = bh >> 4;
    int q0 = qt * 128;
    size_t rb = (size_t)b * s;
    const u16* vtH = VtH + (size_t)bh * 128 * s;
    const u16* vtL = VtL + (size_t)bh * 128 * s;
    u16* PHw = SM + 2 * BUFU + w * 1280;
    u16* PLw = PHw + 640;
    const float scale = 0.08838834764831845f;

    short8 qh[2][4], ql[2][4];
#pragma unroll
    for (int st = 0; st < 2; st++) {
        const u16* qp = QHp + (rb + q0 + st * 64) * 2048 + h * 128 + w * 32;
#pragma unroll
        for (int it = 0; it < 4; it++)
            gload16(qp + (size_t)(it * 16 + grow) * 2048 + sgcol, SM + w * 2048 + it * 512);
        __syncthreads();
#pragma unroll
        for (int ks = 0; ks < 4; ks++)
            qh[st][ks] = *(const short8*)&SM[ks * 2048 + (w * 16 + lr) * 32 + rc];
        if constexpr (PASSES > 1) {
            __syncthreads();
            const u16* qp2 = QLp + (rb + q0 + st * 64) * 2048 + h * 128 + w * 32;
#pragma unroll
            for (int it = 0; it < 4; it++)
                gload16(qp2 + (size_t)(it * 16 + grow) * 2048 + sgcol, SM + w * 2048 + it * 512);
            __syncthreads();
#pragma unroll
            for (int ks = 0; ks < 4; ks++)
                ql[st][ks] = *(const short8*)&SM[ks * 2048 + (w * 16 + lr) * 32 + rc];
        }
        __syncthreads();
    }

    auto kv_stage = [&](int t, int buf) {
        u16* base = SM + buf * BUFU;
        const u16* kp = KHp + (rb + t * 32) * 2048 + h * 128 + w * 32;
        gload16(kp + (size_t)grow * 2048 + sgcol,        base + w * 1024);
        gload16(kp + (size_t)(16 + grow) * 2048 + sgcol, base + w * 1024 + 512);
        const u16* vp = vtH + (size_t)(w * 32) * s + t * 32;
        gload16(vp + (size_t)grow * s + gcol,        base + VOFF + (w * 32) * 32);
        gload16(vp + (size_t)(16 + grow) * s + gcol, base + VOFF + (w * 32 + 16) * 32);
        if constexpr (PASSES > 1) {
            const u16* kp2 = KLp + (rb + t * 32) * 2048 + h * 128 + w * 32;
            gload16(kp2 + (size_t)grow * 2048 + sgcol,        base + 4096 + w * 1024);
            gload16(kp2 + (size_t)(16 + grow) * 2048 + sgcol, base + 4096 + w * 1024 + 512);
            const u16* vp2 = vtL + (size_t)(w * 32) * s + t * 32;
            gload16(vp2 + (size_t)grow * s + gcol,        base + 12288 + (w * 32) * 32);
            gload16(vp2 + (size_t)(16 + grow) * s + gcol, base + 12288 + (w * 32 + 16) * 32);
        }
    };

    f32x4 o_acc[2][8];
#pragma unroll
    for (int st = 0; st < 2; st++)
#pragma unroll
        for (int j = 0; j < 8; j++)
#pragma unroll
            for (int r = 0; r < 4; r++) o_acc[st][j][r] = 0.f;
    float m_run[2][4], l_run[2][4];
#pragma unroll
    for (int st = 0; st < 2; st++)
#pragma unroll
        for (int r = 0; r < 4; r++) { m_run[st][r] = -3.0e38f; l_run[st][r] = 0.f; }

    int nt = (q0 + 128) >> 5;
    int mv0 = mask[rb + lr];
    int mv1 = mask[rb + 16 + lr];
    kv_stage(0, 0);
    for (int t = 0; t < nt; t++) {
        int bsel = t & 1;
        if (t + 1 < nt) {
            kv_stage(t + 1, 1 - bsel);
            if constexpr (PASSES > 1)
                asm volatile("s_waitcnt vmcnt(8)" ::: "memory");
            else
                asm volatile("s_waitcnt vmcnt(4)" ::: "memory");
        } else {
            asm volatile("s_waitcnt vmcnt(0)" ::: "memory");
        }
        BARRIER();
        int nmv0 = mv0, nmv1 = mv1;
        if (t + 1 < nt) {
            nmv0 = mask[rb + (t + 1) * 32 + lr];
            nmv1 = mask[rb + (t + 1) * 32 + 16 + lr];
        }
        const u16* KsH = SM + bsel * BUFU;
        const u16* KsL = KsH + 4096;
        const u16* VsH = SM + bsel * BUFU + VOFF;
        const u16* VsL = SM + bsel * BUFU + 12288;
#pragma unroll
        for (int st = 0; st < 2; st++) {
            if (t * 32 > q0 + st * 64 + w * 16 + 15) continue;
            f32x4 sa[2];
#pragma unroll
            for (int j = 0; j < 2; j++)
#pragma unroll
                for (int r = 0; r < 4; r++) sa[j][r] = 0.f;
#pragma unroll
            for (int j = 0; j < 2; j++) {
#pragma unroll
                for (int ks = 0; ks < 4; ks++) {
                    short8 kb = *(const short8*)&KsH[ks * 1024 + (j * 16 + lr) * 32 + rc];
                    sa[j] = __builtin_amdgcn_mfma_f32_16x16x32_bf16(qh[st][ks], kb, sa[j], 0, 0, 0);
                    if constexpr (PASSES > 1) {
                        short8 kl2 = *(const short8*)&KsL[ks * 1024 + (j * 16 + lr) * 32 + rc];
                        sa[j] = __builtin_amdgcn_mfma_f32_16x16x32_bf16(qh[st][ks], kl2, sa[j], 0, 0, 0);
                        sa[j] = __builtin_amdgcn_mfma_f32_16x16x32_bf16(ql[st][ks], kb, sa[j], 0, 0, 0);
                    }
                }
            }
            float sclv[4];
#pragma unroll
            for (int r = 0; r < 4; r++) {
                int ig = q0 + st * 64 + w * 16 + lq * 4 + r;
                float v0 = (t * 32 + lr <= ig && mv0 > 0) ? sa[0][r] * scale : -1.0e9f;
                float v1 = (t * 32 + 16 + lr <= ig && mv1 > 0) ? sa[1][r] * scale : -1.0e9f;
                float mx = fmaxf(v0, v1);
                mx = fmaxf(mx, __shfl_xor(mx, 1));
                mx = fmaxf(mx, __shfl_xor(mx, 2));
                mx = fmaxf(mx, __shfl_xor(mx, 4));
                mx = fmaxf(mx, __shfl_xor(mx, 8));
                float mo = m_run[st][r];
                float mn = fmaxf(mo, mx);
                float p0 = expf(v0 - mn), p1 = expf(v1 - mn);
                float ps = p0 + p1;
                ps += __shfl_xor(ps, 1);
                ps += __shfl_xor(ps, 2);
                ps += __shfl_xor(ps, 4);
                ps += __shfl_xor(ps, 8);
                sclv[r] = expf(mo - mn);
                m_run[st][r] = mn;
                l_run[st][r] = l_run[st][r] * sclv[r] + ps;
                int prow = lq * 4 + r;
                u16 h0 = bf16rne(p0);
                u16 h1 = bf16rne(p1);
                PHw[prow * 40 + lr] = h0;
                PHw[prow * 40 + 16 + lr] = h1;
                if constexpr (PASSES > 1) {
                    PLw[prow * 40 + lr] = bf16rne(p0 - bf16tof(h0));
                    PLw[prow * 40 + 16 + lr] = bf16rne(p1 - bf16tof(h1));
                }
            }
#pragma unroll
            for (int j = 0; j < 8; j++)
#pragma unroll
                for (int r = 0; r < 4; r++) o_acc[st][j][r] *= sclv[r];
            short8 ph = *(const short8*)&PHw[lr * 40 + lq * 8];
            short8 pl;
            if constexpr (PASSES > 1) pl = *(const short8*)&PLw[lr * 40 + lq * 8];
#pragma unroll
            for (int j = 0; j < 8; j++) {
                int vrow = j * 16 + lr;
                short8 vh = *(const short8*)&VsH[vrow * 32 + rc];
                o_acc[st][j] = __builtin_amdgcn_mfma_f32_16x16x32_bf16(ph, vh, o_acc[st][j], 0, 0, 0);
                if constexpr (PASSES > 1) {
                    short8 vl = *(const short8*)&VsL[vrow * 32 + rc];
                    o_acc[st][j] = __builtin_amdgcn_mfma_f32_16x16x32_bf16(ph, vl, o_acc[st][j], 0, 0, 0);
                    o_acc[st][j] = __builtin_amdgcn_mfma_f32_16x16x32_bf16(pl, vh, o_acc[st][j], 0, 0, 0);
                }
            }
        }
        BARRIER();
        mv0 = nmv0; mv1 = nmv1;
    }
#pragma unroll
    for (int st = 0; st < 2; st++) {
#pragma unroll
        for (int r = 0; r < 4; r++) {
            float linv = 1.0f / l_run[st][r];
            size_t rowoff = (rb + q0 + st * 64 + w * 16 + lq * 4 + r) * 2048 + h * 128 + lr;
#pragma unroll
            for (int j = 0; j < 8; j++) {
                float v = o_acc[st][j][r] * linv;
                u16 hh = bf16rne(v);
                OH[rowoff + j * 16] = hh;
                OL[rowoff + j * 16] = bf16rne(v - bf16tof(hh));
            }
        }
    }
}

// ---------------- fp32 flash attention (tier D fallback) ----------------
__global__ __launch_bounds__(256, 2) void k_attn_f32(const float* __restrict__ Q,
                                                     const float* __restrict__ K,
                                                     const float* __restrict__ V,
                                                     const int* __restrict__ mask,
                                                     u16* __restrict__ OH,
                                                     u16* __restrict__ OL, int s, int ld) {
    int qt = blockIdx.x, bh = blockIdx.y;
    int h = bh & (HH - 1), b = bh >> 4;
    __shared__ float Qs[64][132];
    __shared__ float Ks[32 * 128];
    __shared__ float Vs[32][132];
    __shared__ float Ps[64][36];
    __shared__ float mrow[64], lrow[64];
    int tid = threadIdx.x;
    int tx = tid & 15, ty = tid >> 4;

#pragma unroll
    for (int p = 0; p < 2; p++) {
        int r = p * 32 + (tid >> 3);
        int kb = (tid & 7) * 4;
        const float* src = Q + (size_t)(b * s + qt * 64 + r) * ld + h * DHH;
#pragma unroll
        for (int q = 0; q < 4; q++)
            *(f4*)&Qs[r][kb + 32 * q] = *(const f4*)(src + kb + 32 * q);
    }
    if (tid < 64) { mrow[tid] = -3.0e38f; lrow[tid] = 0.f; }

    float acc[4][8];
#pragma unroll
    for (int i = 0; i < 4; i++)
#pragma unroll
        for (int c = 0; c < 8; c++) acc[i][c] = 0.f;
    const float scale = 0.08838834764831845f;

    int ktmax = 2 * (qt + 1);
    for (int kt = 0; kt < ktmax; kt++) {
        __syncthreads();
#pragma unroll
        for (int p = 0; p < 4; p++) {
            int c = p * 8 + (tid >> 5);
            int kk = (tid & 31) * 4;
            size_t g = (size_t)(b * s + kt * 32 + c) * ld + h * DHH + kk;
            f4 kv = *(const f4*)(K + g);
            int ch = (kk >> 2) ^ (c >> 1);
            *(f4*)&Ks[c * 128 + ch * 4] = kv;
            *(f4*)&Vs[c][kk] = *(const f4*)(V + g);
        }
        __syncthreads();
        float sv[4][2];
#pragma unroll
        for (int i = 0; i < 4; i++) { sv[i][0] = 0.f; sv[i][1] = 0.f; }
        for (int kk = 0; kk < 128; kk += 4) {
            f4 qv[4];
#pragma unroll
            for (int i = 0; i < 4; i++) qv[i] = *(const f4*)&Qs[ty * 4 + i][kk];
#pragma unroll
            for (int j = 0; j < 2; j++) {
                int c = tx * 2 + j;
                int ch = (kk >> 2) ^ (c >> 1);
                f4 kv = *(const f4*)&Ks[c * 128 + ch * 4];
#pragma unroll
                for (int i = 0; i < 4; i++)
                    sv[i][j] += qv[i].x * kv.x + qv[i].y * kv.y +
                                qv[i].z * kv.z + qv[i].w * kv.w;
            }
        }
        float scl[4];
#pragma unroll
        for (int i = 0; i < 4; i++) {
            int r = ty * 4 + i;
            int igl = qt * 64 + r;
#pragma unroll
            for (int j = 0; j < 2; j++) {
                int jg = kt * 32 + tx * 2 + j;
                bool ok = (jg <= igl) && (mask[b * s + jg] > 0);
                sv[i][j] = ok ? sv[i][j] * scale : -1.0e9f;
            }
            float rmax = fmaxf(sv[i][0], sv[i][1]);
            rmax = fmaxf(rmax, __shfl_xor(rmax, 1));
            rmax = fmaxf(rmax, __shfl_xor(rmax, 2));
            rmax = fmaxf(rmax, __shfl_xor(rmax, 4));
            rmax = fmaxf(rmax, __shfl_xor(rmax, 8));
            float mold = mrow[r];
            float mnew = fmaxf(mold, rmax);
            float p0 = expf(sv[i][0] - mnew);
            float p1 = expf(sv[i][1] - mnew);
            float ps = p0 + p1;
            ps += __shfl_xor(ps, 1);
            ps += __shfl_xor(ps, 2);
            ps += __shfl_xor(ps, 4);
            ps += __shfl_xor(ps, 8);
            scl[i] = expf(mold - mnew);
            if (tx == 0) { mrow[r] = mnew; lrow[r] = lrow[r] * scl[i] + ps; }
            float2 pw; pw.x = p0; pw.y = p1;
            *(float2*)&Ps[r][tx * 2] = pw;
        }
        __syncthreads();
#pragma unroll
        for (int i = 0; i < 4; i++) {
            float sc = scl[i];
#pragma unroll
            for (int c = 0; c < 8; c++) acc[i][c] *= sc;
        }
        for (int jj = 0; jj < 32; jj += 4) {
            f4 pv[4];
#pragma unroll
            for (int i = 0; i < 4; i++) pv[i] = *(const f4*)&Ps[ty * 4 + i][jj];
#pragma unroll
            for (int j2 = 0; j2 < 4; j2++) {
                f4 va = *(const f4*)&Vs[jj + j2][tx * 4];
                f4 vb = *(const f4*)&Vs[jj + j2][64 + tx * 4];
#pragma unroll
                for (int i = 0; i < 4; i++) {
                    float p = (&pv[i].x)[j2];
                    acc[i][0] += p * va.x; acc[i][1] += p * va.y;
                    acc[i][2] += p * va.z; acc[i][3] += p * va.w;
                    acc[i][4] += p * vb.x; acc[i][5] += p * vb.y;
                    acc[i][6] += p * vb.z; acc[i][7] += p * vb.w;
                }
            }
        }
    }
    __syncthreads();
#pragma unroll
    for (int i = 0; i < 4; i++) {
        int r = ty * 4 + i;
        float linv = 1.0f / lrow[r];
        size_t ob = (size_t)(b * s + qt * 64 + r) * DD + h * DHH;
        ushort4 h1, l1, h2, l2;
        u16 *h1p = (u16*)&h1, *l1p = (u16*)&l1, *h2p = (u16*)&h2, *l2p = (u16*)&l2;
#pragma unroll
        for (int c = 0; c < 4; c++) {
            float v = acc[i][c] * linv;
            u16 hh = bf16rne(v);
            h1p[c] = hh; l1p[c] = bf16rne(v - bf16tof(hh));
            float v2 = acc[i][c + 4] * linv;
            u16 hh2 = bf16rne(v2);
            h2p[c] = hh2; l2p[c] = bf16rne(v2 - bf16tof(hh2));
        }
        *(ushort4*)&OH[ob + tx * 4] = h1;
        *(ushort4*)&OL[ob + tx * 4] = l1;
        *(ushort4*)&OH[ob + 64 + tx * 4] = h2;
        *(ushort4*)&OL[ob + 64 + tx * 4] = l2;
    }
}

// ---------------- prune scoring / selection ----------------
__global__ __launch_bounds__(256) void k_score(const float* __restrict__ Hb,
                                               const float* __restrict__ srow,
                                               float* __restrict__ sc) {
    int row = blockIdx.x;
    const float* xr = Hb + (size_t)row * DD;
    float ss = 0.f;
    for (int i = threadIdx.x; i < DD / 4; i += blockDim.x) {
        f4 a = ((const f4*)xr)[i];
        f4 w = ((const f4*)srow)[i];
        ss += a.x * w.x + a.y * w.y + a.z * w.z + a.w * w.w;
    }
    for (int o = 32; o > 0; o >>= 1) ss += __shfl_down(ss, o);
    __shared__ float red[4];
    int wid = threadIdx.x >> 6, lane = threadIdx.x & 63;
    if (lane == 0) red[wid] = ss;
    __syncthreads();
    if (threadIdx.x == 0) sc[row] = red[0] + red[1] + red[2] + red[3];
}

__global__ __launch_bounds__(256) void k_rank(const float* __restrict__ sc,
                                              int* __restrict__ flg, int s, int kk) {
    int b = blockIdx.x / s, i = blockIdx.x % s;
    const float* scb = sc + (size_t)b * s;
    float vi = scb[i];
    int cnt = 0;
    for (int j = threadIdx.x; j < s; j += 256) {
        float vj = scb[j];
        if (vj > vi || (vj == vi && j < i)) cnt++;
    }
    for (int o = 32; o > 0; o >>= 1) cnt += __shfl_down(cnt, o);
    __shared__ int red[4];
    int wid = threadIdx.x >> 6, lane = threadIdx.x & 63;
    if (lane == 0) red[wid] = cnt;
    __syncthreads();
    if (threadIdx.x == 0) flg[b * s + i] = ((red[0] + red[1] + red[2] + red[3]) < kk) ? 1 : 0;
}

__global__ void k_compact(const int* __restrict__ flg, int* __restrict__ idx, int s, int kk) {
    int b = blockIdx.x;
    if (threadIdx.x == 0) {
        int p = 0;
        for (int i = 0; i < s; i++)
            if (flg[b * s + i]) idx[b * kk + (p++)] = i;
    }
}

__global__ void k_gather(const float* __restrict__ Hin, const int* __restrict__ idx,
                         float* __restrict__ Hout, int s, int kk) {
    int row = blockIdx.x;
    int b = row / kk, p = row % kk;
    int i = idx[b * kk + p];
    const f4* src = (const f4*)(Hin + (size_t)(b * s + i) * DD);
    f4* dst = (f4*)(Hout + (size_t)row * DD);
    for (int t = threadIdx.x; t < DD / 4; t += blockDim.x) dst[t] = src[t];
}

__global__ void k_gather_mask(const int* __restrict__ Min, const int* __restrict__ idx,
                              int* __restrict__ Mout, int s, int kk) {
    int t = blockIdx.x * blockDim.x + threadIdx.x;
    if (t < BBATCH * kk) {
        int b = t / kk, p = t % kk;
        Mout[t] = Min[b * s + idx[b * kk + p]];
    }
}

// ---------------------------------------------------------------------------
extern "C" void kernel_launch(void* const* d_in, const int* in_sizes, int n_in,
                              void* d_out, int out_size, void* d_ws, size_t ws_size,
                              hipStream_t stream) {
    const int*   input_ids = (const int*)d_in[0];
    const int*   attn_mask = (const int*)d_in[1];
    const float* embed     = (const float*)d_in[2];
    const float* wq        = (const float*)d_in[3];
    const float* wk        = (const float*)d_in[4];
    const float* wv        = (const float*)d_in[5];
    const float* wo        = (const float*)d_in[6];
    const float* wg        = (const float*)d_in[7];
    const float* wu        = (const float*)d_in[8];
    const float* wd        = (const float*)d_in[9];
    const float* ln1       = (const float*)d_in[10];
    const float* ln2       = (const float*)d_in[11];
    const float* lnf       = (const float*)d_in[12];
    const float* lm_head   = (const float*)d_in[13];
    const float* scorer    = (const float*)d_in[14];

    float* ws = (float*)d_ws;
    const size_t R = (size_t)BBATCH * SSEQ * DD;
    const size_t MISC_FLOATS = 2 * SSEQ * 64 + 5 * (size_t)BBATCH * SSEQ + 1024;
    const size_t NEED_A = (14 * R + MISC_FLOATS) * 4;
    const bool bigws = (ws_size >= NEED_A);

    float* H0   = ws;
    float* H1   = ws + R;
    float* CQKV = ws + 2 * R;
    u16*   AH   = (u16*)(ws + 5 * R);
    u16*   AL   = AH + (size_t)4096 * DD;

    u16* QHp = (u16*)(ws + 6 * R);
    u16* QLp = QHp + (size_t)4096 * DD;
    u16* KHp = (u16*)(ws + 7 * R);
    u16* KLp = KHp + (size_t)4096 * DD;
    u16* VtH = (u16*)(ws + 8 * R);
    u16* VtL = VtH + (size_t)4096 * DD;
    u16* FH  = (u16*)(ws + 6 * R);
    u16* FL  = (u16*)(ws + 8 * R);
    u16* WH1 = (u16*)(ws + 10 * R);
    u16* WL1 = WH1 + (size_t)FFF * DD;
    u16* WH2 = (u16*)(ws + 12 * R);
    u16* WL2 = WH2 + (size_t)FFF * DD;
    u16* WDH = (u16*)(ws + 10 * R);
    u16* WDL = WDH + (size_t)DD * FFF;
    u16* WQKVH = (u16*)(ws + 10 * R);
    u16* WQKVL = WQKVH + (size_t)6144 * DD;

    u16* cWgH = (u16*)CQKV;
    u16* cWgL = cWgH + (size_t)2048 * DD;
    u16* cWuH = cWgL + (size_t)2048 * DD;
    u16* cWuL = cWuH + (size_t)2048 * DD;
    u16* cFH  = (u16*)(ws + 3 * R);
    u16* cFL  = cFH + (size_t)4096 * 2048;
    u16* cWdH = (u16*)(ws + 4 * R);
    u16* cWdL = cWdH + (size_t)2048 * DD;

    float* miscB = ws + (bigws ? 14 * R : 6 * R);
    float* COS = miscB;
    float* SIN = COS + SSEQ * 64;
    float* SC  = SIN + SSEQ * 64;
    int*   FLG = (int*)(SC + (size_t)BBATCH * SSEQ);
    int*   IDX = FLG + BBATCH * SSEQ;
    int*   M0  = IDX + BBATCH * SSEQ;
    int*   M1  = M0 + BBATCH * SSEQ;

    k_rope_table<<<(SSEQ * 64 + 255) / 256, 256, 0, stream>>>(COS, SIN);
    k_embed<<<BBATCH * SSEQ, 256, 0, stream>>>(input_ids, embed, H0);
    k_copy_int<<<(BBATCH * SSEQ + 255) / 256, 256, 0, stream>>>(attn_mask, M0, BBATCH * SSEQ);

    float* Hc = H0; float* Nc = H1;
    int*   Mc = M0; int*   Mt = M1;
    int s = SSEQ;

    for (int l = 0; l < LLAYERS; l++) {
        if (l == 1 || l == 2) {
            int pi = l - 1;
            int kk = s / 2;
            k_score<<<BBATCH * s, 256, 0, stream>>>(Hc, scorer + (size_t)pi * 2 * DD, SC);
            k_rank<<<BBATCH * s, 256, 0, stream>>>(SC, FLG, s, kk);
            k_compact<<<BBATCH, 64, 0, stream>>>(FLG, IDX, s, kk);
            k_gather<<<BBATCH * kk, 256, 0, stream>>>(Hc, IDX, Nc, s, kk);
            k_gather_mask<<<(BBATCH * kk + 255) / 256, 256, 0, stream>>>(Mc, IDX, Mt, s, kk);
            { float* t = Hc; Hc = Nc; Nc = t; }
            { int* t = Mc; Mc = Mt; Mt = t; }
            s = kk;
        }
        int rows = BBATCH * s;
        const bool hiP = (l < 2);
        const int wlo = hiP ? 1 : 0;
        const float* Wq = wq + (size_t)l * DD * DD;
        const float* Wk = wk + (size_t)l * DD * DD;
        const float* Wv = wv + (size_t)l * DD * DD;
        const float* Wo = wo + (size_t)l * DD * DD;
        const float* Wg = wg + (size_t)l * DD * FFF;
        const float* Wu = wu + (size_t)l * DD * FFF;
        const float* Wd = wd + (size_t)l * FFF * DD;
        const float* L1 = ln1 + (size_t)l * DD;
        const float* L2 = ln2 + (size_t)l * DD;

        dim3 gWd(DD / 64, DD / 64);

        // ---- QKV projection (fused) ----
        k_rmsnorm_cvt<<<rows, 256, 0, stream>>>(Hc, L1, AH, AL);
        if (bigws) {
            k_cvt_w<<<gWd, 256, 0, stream>>>(Wq, WQKVH, WQKVL, DD, DD, 0, 0, wlo);
            k_cvt_w<<<gWd, 256, 0, stream>>>(Wk, WQKVH, WQKVL, DD, DD, 0, 2048, wlo);
            k_cvt_w<<<gWd, 256, 0, stream>>>(Wv, WQKVH, WQKVL, DD, DD, 0, 4096, wlo);
            if (rows >= 2048) {
                dim3 gQKV(6144 / 256, rows / 256);
                if (hiP) k_bg256<3,0,0><<<gQKV,512,0,stream>>>(AH,AL,WQKVH,WQKVL,CQKV,nullptr,nullptr,nullptr,nullptr,rows,6144,DD,DD);
                else     k_bg256<1,0,0><<<gQKV,512,0,stream>>>(AH,AL,WQKVH,WQKVL,CQKV,nullptr,nullptr,nullptr,nullptr,rows,6144,DD,DD);
            } else {
                dim3 gQKV(6144 / 128, rows / 128);
                k_bgemm<1,0,0><<<gQKV,256,0,stream>>>(AH,AL,WQKVH,WQKVL,nullptr,nullptr,nullptr,CQKV,nullptr,nullptr,rows,6144,DD);
            }
        } else {
            u16* WtH = (u16*)Nc;
            u16* WtL = WtH + (size_t)DD * DD;
            dim3 gG(DD / 128, rows / 128);
            const float* Wqkv[3] = {Wq, Wk, Wv};
            for (int q3 = 0; q3 < 3; q3++) {
                k_cvt_w<<<gWd, 256, 0, stream>>>(Wqkv[q3], WtH, WtL, DD, DD, 0, 0, wlo);
                float* Cb = CQKV + q3 * 2048;
                if (hiP) k_bgemm<3,0,0><<<gG,256,0,stream>>>(AH,AL,WtH,WtL,nullptr,nullptr,nullptr,Cb,nullptr,nullptr,rows,6144,DD);
                else     k_bgemm<1,0,0><<<gG,256,0,stream>>>(AH,AL,WtH,WtL,nullptr,nullptr,nullptr,Cb,nullptr,nullptr,rows,6144,DD);
            }
        }

        // ---- attention ----
        if (bigws) {
            k_cvt_qkr<<<rows, 256, 0, stream>>>(CQKV, COS, SIN, QHp, QLp, KHp, KLp, s);
            k_cvt_vt<<<dim3(s / 64, BBATCH * HH), 256, 0, stream>>>(CQKV, VtH, VtL, s);
            if (hiP) k_attn_mfma<3><<<dim3(s / 128, BBATCH * HH), 256, 0, stream>>>(
                         QHp, QLp, KHp, KLp, VtH, VtL, Mc, AH, AL, s);
            else     k_attn_mfma<1><<<dim3(s / 128, BBATCH * HH), 256, 0, stream>>>(
                         QHp, QLp, KHp, KLp, VtH, VtL, Mc, AH, AL, s);
        } else {
            k_rope<<<rows * HH, 64, 0, stream>>>(CQKV, COS, SIN, s, 6144);
            k_attn_f32<<<dim3(s / 64, BBATCH * HH), 256, 0, stream>>>(
                CQKV, CQKV + 2048, CQKV + 4096, Mc, AH, AL, s, 6144);
        }

        // ---- wo projection + residual (split-K bg256, 256 blocks always) ----
        {
            u16* WtH = bigws ? WQKVH : (u16*)Nc;
            u16* WtL = bigws ? (WQKVH + (size_t)DD * DD) : ((u16*)Nc + (size_t)DD * DD);
            k_cvt_w<<<gWd, 256, 0, stream>>>(Wo, WtH, WtL, DD, DD, 0, 0, wlo);
            if (bigws) {
                int SK = 8192 / rows;          // 4096->2, 2048->4, 1024->8
                float* P = ws + 2 * R;         // CQKV region dead after cvt_qkr/cvt_vt
                dim3 g(DD / 256, rows / 256, SK);
                if (hiP) k_bg256<3,0,0><<<g, 512, 0, stream>>>(AH, AL, WtH, WtL, P,
                                nullptr, nullptr, nullptr, nullptr, rows, DD, DD / SK, DD);
                else     k_bg256<1,0,0><<<g, 512, 0, stream>>>(AH, AL, WtH, WtL, P,
                                nullptr, nullptr, nullptr, nullptr, rows, DD, DD / SK, DD);
                long len = (long)rows * DD;
                k_addN<<<(len / 4 + 255) / 256, 256, 0, stream>>>(Hc, P, len, SK);
            } else {
                dim3 gG(DD / 128, rows / 128);
                if (hiP) k_bgemm<3,1,0><<<gG,256,0,stream>>>(AH,AL,WtH,WtL,nullptr,nullptr,Hc,Hc,nullptr,nullptr,rows,DD,DD);
                else     k_bgemm<1,1,0><<<gG,256,0,stream>>>(AH,AL,WtH,WtL,nullptr,nullptr,Hc,Hc,nullptr,nullptr,rows,DD,DD);
            }
        }

        // ---- MLP ----
        k_rmsnorm_cvt<<<rows, 256, 0, stream>>>(Hc, L2, AH, AL);
        if (bigws && rows >= 2048) {
            k_cvt_w<<<dim3(FFF / 64, DD / 64), 256, 0, stream>>>(Wg, WH1, WL1, DD, FFF, 0, 0, wlo);
            k_cvt_w<<<dim3(FFF / 64, DD / 64), 256, 0, stream>>>(Wu, WH2, WL2, DD, FFF, 0, 0, wlo);
            u16* Gh = (l == 0) ? (u16*)(ws + R) : (u16*)(ws + 2 * R);
            u16* Gl = (u16*)(ws + 3 * R);
            dim3 gMLP(FFF / 256, rows / 256);
            if (hiP) {
                k_bg256<3,1,0><<<gMLP,512,0,stream>>>(AH,AL,WH1,WL1,nullptr,Gh,Gl,nullptr,nullptr,rows,FFF,DD,DD);
                k_bg256<3,1,1><<<gMLP,512,0,stream>>>(AH,AL,WH2,WL2,nullptr,FH,FL,Gh,Gl,rows,FFF,DD,DD);
            } else {
                k_bg256<1,1,0><<<gMLP,512,0,stream>>>(AH,AL,WH1,WL1,nullptr,Gh,Gl,nullptr,nullptr,rows,FFF,DD,DD);
                k_bg256<1,1,1><<<gMLP,512,0,stream>>>(AH,AL,WH2,WL2,nullptr,FH,FL,Gh,Gl,rows,FFF,DD,DD);
            }
            k_cvt_w<<<dim3(DD / 64, FFF / 64), 256, 0, stream>>>(Wd, WDH, WDL, FFF, DD, 0, 0, wlo);
            int SK = 8192 / rows;
            float* P = ws + 2 * R;
            dim3 gD(DD / 256, rows / 256, SK);
            if (hiP) k_bg256<3,0,0><<<gD,512,0,stream>>>(FH,FL,WDH,WDL,P,nullptr,nullptr,nullptr,nullptr,rows,DD,FFF/SK,FFF);
            else     k_bg256<1,0,0><<<gD,512,0,stream>>>(FH,FL,WDH,WDL,P,nullptr,nullptr,nullptr,nullptr,rows,DD,FFF/SK,FFF);
            long len = (long)rows * DD;
            k_addN<<<(len / 4 + 255) / 256, 256, 0, stream>>>(Hc, P, len, SK);
        } else if (bigws) {
            // L2/L3 (rows 1024): gate/up 128^2 DUAL (512 blocks) + split-K down
            k_cvt_w<<<dim3(FFF / 64, DD / 64), 256, 0, stream>>>(Wg, WH1, WL1, DD, FFF, 0, 0, wlo);
            k_cvt_w<<<dim3(FFF / 64, DD / 64), 256, 0, stream>>>(Wu, WH2, WL2, DD, FFF, 0, 0, wlo);
            k_bgemm<1,0,1><<<dim3(FFF/128, rows/128),256,0,stream>>>(AH,AL,WH1,WL1,WH2,WL2,nullptr,nullptr,FH,FL,rows,FFF,DD);
            k_cvt_w<<<dim3(DD / 64, FFF / 64), 256, 0, stream>>>(Wd, WDH, WDL, FFF, DD, 0, 0, wlo);
            int SK = 8192 / rows;              // 8 -> grid (8,4,8) = 256 blocks
            float* P = ws + 2 * R;
            dim3 gD(DD / 256, rows / 256, SK);
            k_bg256<1,0,0><<<gD,512,0,stream>>>(FH,FL,WDH,WDL,P,nullptr,nullptr,nullptr,nullptr,rows,DD,FFF/SK,FFF);
            long len = (long)rows * DD;
            k_addN<<<(len / 4 + 255) / 256, 256, 0, stream>>>(Hc, P, len, SK);
        } else {
            for (int ffc = 0; ffc < FFF; ffc += 2048) {
                k_cvt_w<<<dim3(2048 / 64, DD / 64), 256, 0, stream>>>(Wg, cWgH, cWgL, DD, FFF, ffc, 0, wlo);
                k_cvt_w<<<dim3(2048 / 64, DD / 64), 256, 0, stream>>>(Wu, cWuH, cWuL, DD, FFF, ffc, 0, wlo);
                if (hiP) k_bgemm<3,0,1><<<dim3(16, rows/128),256,0,stream>>>(AH,AL,cWgH,cWgL,cWuH,cWuL,nullptr,nullptr,cFH,cFL,rows,2048,DD);
                else     k_bgemm<1,0,1><<<dim3(16, rows/128),256,0,stream>>>(AH,AL,cWgH,cWgL,cWuH,cWuL,nullptr,nullptr,cFH,cFL,rows,2048,DD);
                k_cvt_w<<<dim3(DD / 64, 2048 / 64), 256, 0, stream>>>(Wd + (size_t)ffc * DD, cWdH, cWdL, 2048, DD, 0, 0, wlo);
                if (hiP) k_bgemm<3,1,0><<<dim3(DD/128, rows/128),256,0,stream>>>(cFH,cFL,cWdH,cWdL,nullptr,nullptr,Hc,Hc,nullptr,nullptr,rows,DD,2048);
                else     k_bgemm<1,1,0><<<dim3(DD/128, rows/128),256,0,stream>>>(cFH,cFL,cWdH,cWdL,nullptr,nullptr,Hc,Hc,nullptr,nullptr,rows,DD,2048);
            }
        }
    }

    // ---- final rmsnorm + lm_head ----
    int rows = BBATCH * s;   // 1024
    u16* AHf = (u16*)Nc;
    u16* ALf = AHf + (size_t)rows * DD;
    u16* LmH = bigws ? (u16*)(ws + 6 * R) : (u16*)CQKV;
    k_rmsnorm_cvt<<<rows, 256, 0, stream>>>(Hc, lnf, AHf, ALf);
    k_cvt_w<<<dim3(VV / 64, DD / 64), 256, 0, stream>>>(lm_head, LmH, LmH, DD, VV, 0, 0, 0);
    if (bigws) {
        k_bg256<1,0,0><<<dim3(VV / 256, rows / 256), 512, 0, stream>>>(
            AHf, ALf, LmH, LmH, (float*)d_out, nullptr, nullptr, nullptr, nullptr,
            rows, VV, DD, DD);
    } else {
        k_bgemm<1,0,0><<<dim3(VV / 128, rows / 128), 256, 0, stream>>>(
            AHf, ALf, LmH, LmH, nullptr, nullptr, nullptr, (float*)d_out,
            nullptr, nullptr, rows, VV, DD);
    }
}